// Round 2
// baseline (2954.411 us; speedup 1.0000x reference)
//
#include <hip/hip_runtime.h>
#include <cstdint>
#include <cstddef>

#define GRAPH_SIZE 100
#define CH 64
#define N_GRAPHS 4096
#define N_NODES (N_GRAPHS * GRAPH_SIZE)   // 409600
#define DEG 16
#define N_EDGES (N_NODES * DEG)           // 6553600
#define BN_EPS 1e-3f

#define NBUCKET 2048          // 2 graphs (200 nodes) per bucket
#define NODES_PER_BUCKET 200
#define PCHUNK 12800          // edges per partition WG
#define NPWG (N_EDGES / PCHUNK)   // 512

// ---------------------------------------------------------------- count
// Per-WG LDS histogram of receiver buckets -> wg_hist[w][b]. No global atomics.
__global__ __launch_bounds__(256) void count_kernel(const int* __restrict__ recv,
                                                    unsigned* __restrict__ wg_hist) {
  __shared__ unsigned lh[NBUCKET];
  int tid = threadIdx.x, w = blockIdx.x;
  for (int i = tid; i < NBUCKET; i += 256) lh[i] = 0;
  __syncthreads();
  size_t base = (size_t)w * PCHUNK;
  for (int i = tid; i < PCHUNK; i += 256)
    atomicAdd(&lh[recv[base + i] / NODES_PER_BUCKET], 1u);
  __syncthreads();
  for (int i = tid; i < NBUCKET; i += 256) wg_hist[(size_t)w * NBUCKET + i] = lh[i];
}

// ---------------------------------------------------------------- scans
// In-place: wg_hist[w][b] -> exclusive prefix over w (per bucket); totals out.
__global__ __launch_bounds__(256) void scan_wg_kernel(unsigned* __restrict__ wg_hist,
                                                      unsigned* __restrict__ gtotal) {
  int b = blockIdx.x * 256 + threadIdx.x;   // grid = NBUCKET/256 = 8
  unsigned run = 0;
  for (int w = 0; w < NPWG; w++) {
    size_t idx = (size_t)w * NBUCKET + b;
    unsigned c = wg_hist[idx];
    wg_hist[idx] = run;
    run += c;
  }
  gtotal[b] = run;
}

// Exclusive scan of gtotal[2048] -> gbase[2048]. Single WG.
__global__ __launch_bounds__(256) void scan_bucket_kernel(const unsigned* __restrict__ gtotal,
                                                          unsigned* __restrict__ gbase) {
  __shared__ unsigned tmp[256];
  int tid = threadIdx.x;
  unsigned my[8], s8 = 0;
#pragma unroll
  for (int j = 0; j < 8; j++) { my[j] = gtotal[tid * 8 + j]; s8 += my[j]; }
  tmp[tid] = s8;
  __syncthreads();
  unsigned acc = s8;
  for (int d = 1; d < 256; d <<= 1) {
    unsigned t = (tid >= d) ? tmp[tid - d] : 0;
    __syncthreads();
    acc += t;
    tmp[tid] = acc;
    __syncthreads();
  }
  unsigned run = tmp[tid] - s8;   // exclusive over threads
#pragma unroll
  for (int j = 0; j < 8; j++) { gbase[tid * 8 + j] = run; run += my[j]; }
}

// ---------------------------------------------------------------- partition
// LDS counting-sort of each 12800-edge chunk, coalesced u16 write-out.
__global__ __launch_bounds__(256) void partition_kernel(const int* __restrict__ recv,
                                                        const int* __restrict__ send,
                                                        const unsigned* __restrict__ wg_hist,
                                                        const unsigned* __restrict__ gbase,
                                                        unsigned short* __restrict__ sortedu16) {
  __shared__ unsigned cur[NBUCKET];     // counts -> offsets -> cursors -> ends
  __shared__ unsigned tmp[256];
  __shared__ unsigned stage[PCHUNK];
  int tid = threadIdx.x, w = blockIdx.x;
  size_t base = (size_t)w * PCHUNK;

  for (int i = tid; i < NBUCKET; i += 256) cur[i] = 0;
  __syncthreads();
  for (int i = tid; i < PCHUNK; i += 256)
    atomicAdd(&cur[recv[base + i] / NODES_PER_BUCKET], 1u);
  __syncthreads();

  // exclusive scan of cur[2048] (natural bucket order)
  unsigned my[8], s8 = 0;
#pragma unroll
  for (int j = 0; j < 8; j++) { my[j] = cur[tid * 8 + j]; s8 += my[j]; }
  tmp[tid] = s8;
  __syncthreads();
  unsigned acc = s8;
  for (int d = 1; d < 256; d <<= 1) {
    unsigned t = (tid >= d) ? tmp[tid - d] : 0;
    __syncthreads();
    acc += t;
    tmp[tid] = acc;
    __syncthreads();
  }
  unsigned run = tmp[tid] - s8;
#pragma unroll
  for (int j = 0; j < 8; j++) { cur[tid * 8 + j] = run; run += my[j]; }
  __syncthreads();

  // scatter records into LDS, grouped by bucket
  for (int i = tid; i < PCHUNK; i += 256) {
    int r = recv[base + i];
    int s = send[base + i];
    unsigned b = (unsigned)r / NODES_PER_BUCKET;
    unsigned rl = (unsigned)r - b * NODES_PER_BUCKET;   // 0..199
    unsigned sl = (unsigned)s % GRAPH_SIZE;             // 0..99
    unsigned pos = atomicAdd(&cur[b], 1u);
    stage[pos] = (b << 16) | (sl << 8) | rl;
  }
  __syncthreads();
  // cur[b] now == exclusive end of bucket b within this chunk

  const unsigned* wrow = wg_hist + (size_t)w * NBUCKET;
  for (int p = tid; p < PCHUNK; p += 256) {
    unsigned rec = stage[p];
    unsigned b = rec >> 16;
    unsigned start = (b > 0) ? cur[b - 1] : 0;
    unsigned dest = gbase[b] + wrow[b] + ((unsigned)p - start);
    sortedu16[dest] = (unsigned short)(rec & 0xFFFFu);
  }
}

// --------------------------------------------- fused aggregate+conv+BN+ELU
// One WG per bucket: agg[200][64] fp32 in LDS (51.2 KB), 3 WG/CU.
__global__ __launch_bounds__(256) void aggconv_kernel(
    const float* __restrict__ x, const unsigned* __restrict__ gbase,
    const unsigned* __restrict__ gtotal, const unsigned short* __restrict__ sorted,
    const float* __restrict__ W1, const float* __restrict__ b1,
    const float* __restrict__ gamma, const float* __restrict__ beta,
    const float* __restrict__ bn_mean, const float* __restrict__ bn_var,
    float* __restrict__ h) {
  __shared__ float agg[NODES_PER_BUCKET * 64];   // 51200 B
  int tid = threadIdx.x, lane = tid & 63, wv = tid >> 6;
  int b = blockIdx.x;

  for (int i = tid; i < NODES_PER_BUCKET * 64; i += 256) agg[i] = 0.f;
  __syncthreads();

  unsigned e0 = gbase[b], cnt = gtotal[b];
  size_t xbase = (size_t)b * NODES_PER_BUCKET * 64;
  for (unsigned blk = wv * 64u; blk < cnt; blk += 256u) {
    unsigned n = cnt - blk;
    if (n > 64u) n = 64u;
    int rec = (lane < (int)n) ? (int)sorted[e0 + blk + lane] : 0;
    for (unsigned j = 0; j < n; j++) {
      unsigned v = (unsigned)__shfl(rec, (int)j);
      unsigned rl = v & 0xFFu;          // 0..199
      unsigned sl = (v >> 8) & 0x7Fu;   // 0..99
      unsigned srow = ((rl >= 100u) ? 100u : 0u) + sl;
      float xv = x[xbase + srow * 64u + lane];
      atomicAdd(&agg[rl * 64u + lane], xv);
    }
  }
  __syncthreads();

  float w[64];
#pragma unroll
  for (int i = 0; i < 64; i++) w[i] = W1[i * 64 + lane];
  float scale = gamma[lane] * rsqrtf(bn_var[lane] + BN_EPS);
  float mb = bn_mean[lane], bt = beta[lane], bias1 = b1[lane];

  for (int n = wv; n < NODES_PER_BUCKET; n += 4) {
    float acc = agg[n * 64 + lane];
    float hv = bias1;
#pragma unroll
    for (int i = 0; i < 64; i++) hv = fmaf(__shfl(acc, i), w[i], hv);
    hv = (hv - mb) * scale + bt;
    hv = (hv > 0.f) ? hv : expm1f(hv);
    h[((size_t)b * NODES_PER_BUCKET + n) * 64 + lane] = hv;
  }
}

// ---------------------------------------------------------------- GEMM2
// Cp[ks][4096][256] partial = A[4096,6400] @ B[6400,256], K split by 4.
// 64M x 256N tile, 8x8 per-thread, reg-prefetch double buffer.
#define G2_K 6400
#define G2_SPLIT 4
#define G2_KSLICE (G2_K / G2_SPLIT)   // 1600
__global__ __launch_bounds__(256) void gemm2_kernel(const float* __restrict__ A,
                                                    const float* __restrict__ B,
                                                    float* __restrict__ Cp) {
  __shared__ float As[16][68];
  __shared__ float Bs[16][256];
  int tid = threadIdx.x;
  int tx = tid & 31;        // n-group: cols tx + 32j
  int ty = tid >> 5;        // m-group: rows ty*8 + i
  int bm = blockIdx.x * 64;
  int k0base = blockIdx.y * G2_KSLICE;

  float acc[8][8] = {};

  int lm = tid >> 2;                 // 0..63
  int lk = (tid & 3) * 4;            // 0,4,8,12
  const float* Aptr = A + (size_t)(bm + lm) * G2_K + k0base + lk;
  const float* Bptr = B + (size_t)k0base * 256 + tid;

  float4 apre = *(const float4*)Aptr;
  float bpre[16];
#pragma unroll
  for (int r = 0; r < 16; r++) bpre[r] = Bptr[r * 256];

  const int NT = G2_KSLICE / 16;     // 100
  for (int kt = 0; kt < NT; kt++) {
    As[lk + 0][lm] = apre.x;
    As[lk + 1][lm] = apre.y;
    As[lk + 2][lm] = apre.z;
    As[lk + 3][lm] = apre.w;
#pragma unroll
    for (int r = 0; r < 16; r++) Bs[r][tid] = bpre[r];
    __syncthreads();

    if (kt + 1 < NT) {
      apre = *(const float4*)(Aptr + (kt + 1) * 16);
#pragma unroll
      for (int r = 0; r < 16; r++) bpre[r] = Bptr[((kt + 1) * 16 + r) * 256];
    }

#pragma unroll
    for (int kk = 0; kk < 16; kk++) {
      float a[8], bf[8];
#pragma unroll
      for (int i = 0; i < 8; i++) a[i] = As[kk][ty * 8 + i];
#pragma unroll
      for (int j = 0; j < 8; j++) bf[j] = Bs[kk][tx + 32 * j];
#pragma unroll
      for (int i = 0; i < 8; i++)
#pragma unroll
        for (int j = 0; j < 8; j++) acc[i][j] = fmaf(a[i], bf[j], acc[i][j]);
    }
    __syncthreads();
  }

  float* out = Cp + (size_t)blockIdx.y * N_GRAPHS * 256;
#pragma unroll
  for (int i = 0; i < 8; i++)
#pragma unroll
    for (int j = 0; j < 8; j++)
      out[(size_t)(bm + ty * 8 + i) * 256 + tx + 32 * j] = acc[i][j];
}

// split-K reduce + bias + relu
__global__ __launch_bounds__(256) void reduce_kernel(const float* __restrict__ Cp,
                                                     const float* __restrict__ bias,
                                                     float* __restrict__ out1) {
  int i = blockIdx.x * 256 + threadIdx.x;   // over 4096*256
  const size_t S = (size_t)N_GRAPHS * 256;
  float v = Cp[i] + Cp[S + i] + Cp[2 * S + i] + Cp[3 * S + i] + bias[i & 255];
  out1[i] = fmaxf(v, 0.f);
}

// ---------------------------------------------------------------- tail
__global__ __launch_bounds__(256) void tail_kernel(const float* __restrict__ out1,
                                                   const float* __restrict__ Wd2,
                                                   const float* __restrict__ bd2,
                                                   const float* __restrict__ Wd3,
                                                   const float* __restrict__ bd3,
                                                   float* __restrict__ out) {
  int lane = threadIdx.x & 63;
  int wave = threadIdx.x >> 6;
  int row = blockIdx.x * 4 + wave;

  const float* in = out1 + (size_t)row * 256;
  float i0 = in[lane];
  float i1 = in[64 + lane];
  float i2 = in[128 + lane];
  float i3 = in[192 + lane];

  float a0 = bd2[lane];
  float a1 = bd2[64 + lane];
#pragma unroll
  for (int i = 0; i < 64; i++) {
    float v0 = __shfl(i0, i);
    a0 = fmaf(v0, Wd2[(i)*128 + lane], a0);
    a1 = fmaf(v0, Wd2[(i)*128 + 64 + lane], a1);
    float v1 = __shfl(i1, i);
    a0 = fmaf(v1, Wd2[(64 + i) * 128 + lane], a0);
    a1 = fmaf(v1, Wd2[(64 + i) * 128 + 64 + lane], a1);
    float v2 = __shfl(i2, i);
    a0 = fmaf(v2, Wd2[(128 + i) * 128 + lane], a0);
    a1 = fmaf(v2, Wd2[(128 + i) * 128 + 64 + lane], a1);
    float v3 = __shfl(i3, i);
    a0 = fmaf(v3, Wd2[(192 + i) * 128 + lane], a0);
    a1 = fmaf(v3, Wd2[(192 + i) * 128 + 64 + lane], a1);
  }
  a0 = fmaxf(a0, 0.f);
  a1 = fmaxf(a1, 0.f);
  float p = a0 * Wd3[lane] + a1 * Wd3[64 + lane];
#pragma unroll
  for (int m = 32; m >= 1; m >>= 1) p += __shfl_xor(p, m);
  if (lane == 0) out[row] = 1.f / (1.f + expf(-(p + bd3[0])));
}

// ---------------------------------------------------------------- launcher
extern "C" void kernel_launch(void* const* d_in, const int* in_sizes, int n_in,
                              void* d_out, int out_size, void* d_ws, size_t ws_size,
                              hipStream_t stream) {
  const float* x        = (const float*)d_in[0];
  const int*   senders  = (const int*)d_in[1];
  const int*   receivers= (const int*)d_in[2];
  const float* W1       = (const float*)d_in[3];
  const float* b1       = (const float*)d_in[4];
  const float* gamma    = (const float*)d_in[5];
  const float* beta     = (const float*)d_in[6];
  const float* bn_mean  = (const float*)d_in[7];
  const float* bn_var   = (const float*)d_in[8];
  const float* W_d1     = (const float*)d_in[9];
  const float* b_d1     = (const float*)d_in[10];
  const float* W_d2     = (const float*)d_in[11];
  const float* b_d2     = (const float*)d_in[12];
  const float* W_d3     = (const float*)d_in[13];
  const float* b_d3     = (const float*)d_in[14];
  float* out = (float*)d_out;

  // workspace layout (sorted aliases Cp: sorted is dead before gemm2 runs)
  char* ws = (char*)d_ws;
  float* h       = (float*)ws;  ws += (size_t)N_NODES * 64 * 4;          // 104,857,600
  unsigned* wg_hist = (unsigned*)ws; ws += (size_t)NPWG * NBUCKET * 4;   // 4,194,304
  unsigned* gtotal  = (unsigned*)ws; ws += NBUCKET * 4;
  unsigned* gbase   = (unsigned*)ws; ws += NBUCKET * 4;
  char* region4 = ws;
  unsigned short* sortedu16 = (unsigned short*)region4;                  // 13,107,200
  float* Cp   = (float*)region4;                                         // 16,777,216
  float* out1 = (float*)(region4 + (size_t)G2_SPLIT * N_GRAPHS * 256 * 4); // 4,194,304

  count_kernel<<<NPWG, 256, 0, stream>>>(receivers, wg_hist);
  scan_wg_kernel<<<NBUCKET / 256, 256, 0, stream>>>(wg_hist, gtotal);
  scan_bucket_kernel<<<1, 256, 0, stream>>>(gtotal, gbase);
  partition_kernel<<<NPWG, 256, 0, stream>>>(receivers, senders, wg_hist, gbase, sortedu16);
  aggconv_kernel<<<NBUCKET, 256, 0, stream>>>(x, gbase, gtotal, sortedu16, W1, b1,
                                              gamma, beta, bn_mean, bn_var, h);
  gemm2_kernel<<<dim3(N_GRAPHS / 64, G2_SPLIT), 256, 0, stream>>>(h, W_d1, Cp);
  reduce_kernel<<<(N_GRAPHS * 256) / 256, 256, 0, stream>>>(Cp, b_d1, out1);
  tail_kernel<<<N_GRAPHS / 4, 256, 0, stream>>>(out1, W_d2, b_d2, W_d3, b_d3, out);
}

// Round 3
// 798.025 us; speedup vs baseline: 3.7022x; 3.7022x over previous
//
#include <hip/hip_runtime.h>
#include <cstdint>
#include <cstddef>

#define GRAPH_SIZE 100
#define N_GRAPHS 4096
#define N_NODES (N_GRAPHS * GRAPH_SIZE)   // 409600
#define DEG 16
#define N_EDGES (N_NODES * DEG)           // 6553600
#define BN_EPS 1e-3f

#define NB1 1024                  // level-1 buckets: 4 graphs / 400 nodes each
#define NPB 400                   // nodes per bucket
#define PCHUNK 12800              // edges per partition WG
#define NPWG (N_EDGES / PCHUNK)   // 512

// ---------------------------------------------------------------- count1
// Per-WG LDS histogram of receiver buckets. No global atomics.
__global__ __launch_bounds__(256) void count1_kernel(const int* __restrict__ recv,
                                                     unsigned* __restrict__ wg_hist) {
  __shared__ unsigned lh[NB1];
  int tid = threadIdx.x, w = blockIdx.x;
  for (int i = tid; i < NB1; i += 256) lh[i] = 0;
  __syncthreads();
  size_t base = (size_t)w * PCHUNK;
  for (int i = tid; i < PCHUNK; i += 256)
    atomicAdd(&lh[(unsigned)recv[base + i] / NPB], 1u);
  __syncthreads();
  for (int i = tid; i < NB1; i += 256) wg_hist[(size_t)w * NB1 + i] = lh[i];
}

// ---------------------------------------------------------------- scans
// wg_hist[w][b] -> exclusive prefix over w (per bucket); per-bucket totals out.
__global__ __launch_bounds__(256) void scan_wg_kernel(unsigned* __restrict__ wg_hist,
                                                      unsigned* __restrict__ gtotal) {
  int b = blockIdx.x * 256 + threadIdx.x;   // grid = NB1/256 = 4
  unsigned run = 0;
  for (int w = 0; w < NPWG; w++) {
    size_t idx = (size_t)w * NB1 + b;
    unsigned c = wg_hist[idx];
    wg_hist[idx] = run;
    run += c;
  }
  gtotal[b] = run;
}

// Exclusive scan of gtotal[1024] -> gbase[1024]. Single WG.
__global__ __launch_bounds__(256) void scan_bucket_kernel(const unsigned* __restrict__ gtotal,
                                                          unsigned* __restrict__ gbase) {
  __shared__ unsigned tmp[256];
  int tid = threadIdx.x;
  unsigned my[4], s4 = 0;
#pragma unroll
  for (int j = 0; j < 4; j++) { my[j] = gtotal[tid * 4 + j]; s4 += my[j]; }
  tmp[tid] = s4;
  __syncthreads();
  unsigned acc = s4;
  for (int d = 1; d < 256; d <<= 1) {
    unsigned t = (tid >= d) ? tmp[tid - d] : 0;
    __syncthreads();
    acc += t;
    tmp[tid] = acc;
    __syncthreads();
  }
  unsigned run = tmp[tid] - s4;
#pragma unroll
  for (int j = 0; j < 4; j++) { gbase[tid * 4 + j] = run; run += my[j]; }
}

// ---------------------------------------------------------------- partition1
// LDS counting-sort of each 12800-edge chunk into 1024 buckets; u16 records out.
// u16 record = gib(2b) << 14 | sl(7b) << 7 | rl(7b).
__global__ __launch_bounds__(256) void partition1_kernel(const int* __restrict__ recv,
                                                         const int* __restrict__ send,
                                                         const unsigned* __restrict__ wg_hist,
                                                         const unsigned* __restrict__ gbase,
                                                         unsigned short* __restrict__ midrec) {
  __shared__ unsigned cur[NB1];
  __shared__ unsigned tmp[256];
  __shared__ unsigned stage[PCHUNK];
  int tid = threadIdx.x, w = blockIdx.x;
  size_t base = (size_t)w * PCHUNK;

  for (int i = tid; i < NB1; i += 256) cur[i] = 0;
  __syncthreads();
  for (int i = tid; i < PCHUNK; i += 256)
    atomicAdd(&cur[(unsigned)recv[base + i] / NPB], 1u);
  __syncthreads();

  unsigned my[4], s4 = 0;
#pragma unroll
  for (int j = 0; j < 4; j++) { my[j] = cur[tid * 4 + j]; s4 += my[j]; }
  tmp[tid] = s4;
  __syncthreads();
  unsigned acc = s4;
  for (int d = 1; d < 256; d <<= 1) {
    unsigned t = (tid >= d) ? tmp[tid - d] : 0;
    __syncthreads();
    acc += t;
    tmp[tid] = acc;
    __syncthreads();
  }
  unsigned run = tmp[tid] - s4;
#pragma unroll
  for (int j = 0; j < 4; j++) { cur[tid * 4 + j] = run; run += my[j]; }
  __syncthreads();

  for (int i = tid; i < PCHUNK; i += 256) {
    unsigned r = (unsigned)recv[base + i];
    unsigned s = (unsigned)send[base + i];
    unsigned b = r / NPB;
    unsigned rin = r - b * NPB;          // 0..399
    unsigned gib = rin / 100;            // 0..3
    unsigned rl = rin - gib * 100;       // 0..99
    unsigned sl = s - (s / 100) * 100;   // 0..99
    unsigned pos = atomicAdd(&cur[b], 1u);
    stage[pos] = (b << 16) | (gib << 14) | (sl << 7) | rl;
  }
  __syncthreads();
  // cur[b] == exclusive end of bucket b within this chunk

  const unsigned* wrow = wg_hist + (size_t)w * NB1;
  for (int p = tid; p < PCHUNK; p += 256) {
    unsigned rec = stage[p];
    unsigned b = rec >> 16;
    unsigned start = (b > 0) ? cur[b - 1] : 0;
    unsigned dest = gbase[b] + wrow[b] + ((unsigned)p - start);
    midrec[dest] = (unsigned short)(rec & 0xFFFFu);
  }
}

// ---------------------------------------------------------------- sort2
// Per-bucket (4 graphs, ~6400 edges) LDS sort by receiver node; emits final
// u16 = (sl<<7)|rl grouped by node, plus per-node CSR offsets noff[].
#define S2CAP 8192
__global__ __launch_bounds__(256) void sort2_kernel(const unsigned short* __restrict__ midrec,
                                                    const unsigned* __restrict__ gtotal,
                                                    const unsigned* __restrict__ gbase,
                                                    unsigned short* __restrict__ sorted,
                                                    unsigned* __restrict__ noff) {
  __shared__ unsigned hist[512];
  __shared__ unsigned tmp[256];
  __shared__ unsigned short dst[S2CAP];
  int tid = threadIdx.x, b = blockIdx.x;
  unsigned cnt = gtotal[b];
  if (cnt > S2CAP) cnt = S2CAP;   // safety clamp (22 sigma above mean)
  unsigned gb = gbase[b];

  hist[tid] = 0; hist[256 + tid] = 0;
  __syncthreads();
  for (unsigned i = tid; i < cnt; i += 256) {
    unsigned rec = midrec[gb + i];
    unsigned nib = (rec >> 14) * 100 + (rec & 127u);   // node-in-bucket 0..399
    atomicAdd(&hist[nib], 1u);
  }
  __syncthreads();

  unsigned c0 = hist[2 * tid], c1 = hist[2 * tid + 1];
  unsigned s2 = c0 + c1;
  tmp[tid] = s2;
  __syncthreads();
  unsigned acc = s2;
  for (int d = 1; d < 256; d <<= 1) {
    unsigned t = (tid >= d) ? tmp[tid - d] : 0;
    __syncthreads();
    acc += t;
    tmp[tid] = acc;
    __syncthreads();
  }
  unsigned base0 = acc - s2;
  hist[2 * tid] = base0;
  hist[2 * tid + 1] = base0 + c0;
  if (2 * tid < NPB)     noff[(size_t)b * NPB + 2 * tid] = gb + base0;
  if (2 * tid + 1 < NPB) noff[(size_t)b * NPB + 2 * tid + 1] = gb + base0 + c0;
  if (b == 0 && tid == 0) noff[N_NODES] = N_EDGES;   // sentinel
  __syncthreads();

  for (unsigned i = tid; i < cnt; i += 256) {
    unsigned rec = midrec[gb + i];
    unsigned nib = (rec >> 14) * 100 + (rec & 127u);
    unsigned pos = atomicAdd(&hist[nib], 1u);
    if (pos < S2CAP) dst[pos] = (unsigned short)(rec & 0x3FFFu);
  }
  __syncthreads();
  for (unsigned i = tid; i < cnt; i += 256) sorted[gb + i] = dst[i];
}

// --------------------------------------------- fused aggregate+conv+BN+ELU
// One WG per graph. x block staged in LDS; CSR per receiver -> register acc;
// conv via agg-row broadcast reads + W1 column in 64 VGPRs (conv commutes
// with segment-sum: agg@W1 done per node after aggregation).
__global__ __launch_bounds__(256) void aggconv_kernel(
    const float* __restrict__ x, const unsigned* __restrict__ noff,
    const unsigned short* __restrict__ sorted,
    const float* __restrict__ W1, const float* __restrict__ b1,
    const float* __restrict__ gamma, const float* __restrict__ beta,
    const float* __restrict__ bn_mean, const float* __restrict__ bn_var,
    float* __restrict__ h) {
  __shared__ float xs[6400];    // 25.6 KB: graph's x block
  __shared__ float agg[6400];   // 25.6 KB: aggregated rows
  int tid = threadIdx.x, lane = tid & 63, wv = tid >> 6;
  int g = blockIdx.x;
  size_t gb64 = (size_t)g * 6400;

  // stage x block (coalesced float4)
  const float4* xsrc = (const float4*)(x + gb64);
  for (int i = tid; i < 1600; i += 256) ((float4*)xs)[i] = xsrc[i];

  float w[64];
#pragma unroll
  for (int i = 0; i < 64; i++) w[i] = W1[i * 64 + lane];
  float scale = gamma[lane] * rsqrtf(bn_var[lane] + BN_EPS);
  float mb = bn_mean[lane], bt = beta[lane], bias1 = b1[lane];
  unsigned nb = (unsigned)g * 100;
  __syncthreads();

  // phase 2: aggregate per receiver (CSR), acc in registers
  for (int n = wv; n < 100; n += 4) {
    unsigned ebeg = noff[nb + n], eend = noff[nb + n + 1];
    float acc = 0.f;
    for (unsigned e = ebeg; e < eend; e += 4) {
      unsigned last = eend - 1;
      unsigned i1 = e + 1 < last ? e + 1 : last;
      unsigned i2 = e + 2 < last ? e + 2 : last;
      unsigned i3 = e + 3 < last ? e + 3 : last;
      unsigned r0 = sorted[e];
      unsigned r1 = sorted[i1];
      unsigned r2 = sorted[i2];
      unsigned r3 = sorted[i3];
      float v0 = xs[(r0 >> 7) * 64 + lane];
      float v1 = xs[(r1 >> 7) * 64 + lane];
      float v2 = xs[(r2 >> 7) * 64 + lane];
      float v3 = xs[(r3 >> 7) * 64 + lane];
      acc += v0;
      acc += (e + 1 < eend) ? v1 : 0.f;
      acc += (e + 2 < eend) ? v2 : 0.f;
      acc += (e + 3 < eend) ? v3 : 0.f;
    }
    agg[n * 64 + lane] = acc;
  }
  __syncthreads();

  // phase 3: conv (matvec per node via LDS broadcast) + BN + ELU + store
  for (int n = wv; n < 100; n += 4) {
    float hv = bias1;
#pragma unroll
    for (int q = 0; q < 16; q++) {
      float4 av = *(const float4*)&agg[n * 64 + q * 4];
      hv = fmaf(av.x, w[q * 4 + 0], hv);
      hv = fmaf(av.y, w[q * 4 + 1], hv);
      hv = fmaf(av.z, w[q * 4 + 2], hv);
      hv = fmaf(av.w, w[q * 4 + 3], hv);
    }
    hv = (hv - mb) * scale + bt;
    hv = (hv > 0.f) ? hv : expm1f(hv);
    h[gb64 + (size_t)n * 64 + lane] = hv;
  }
}

// ---------------------------------------------------------------- GEMM2
// Cp[ks][4096][256] partial = A[4096,6400] @ B[6400,256], K split by 8.
#define G2_K 6400
#define G2_SPLIT 8
#define G2_KSLICE (G2_K / G2_SPLIT)   // 800
__global__ __launch_bounds__(256) void gemm2_kernel(const float* __restrict__ A,
                                                    const float* __restrict__ B,
                                                    float* __restrict__ Cp) {
  __shared__ float As[16][68];
  __shared__ float Bs[16][256];
  int tid = threadIdx.x;
  int tx = tid & 31;
  int ty = tid >> 5;
  int bm = blockIdx.x * 64;
  int k0base = blockIdx.y * G2_KSLICE;

  float acc[8][8] = {};

  int lm = tid >> 2;
  int lk = (tid & 3) * 4;
  const float* Aptr = A + (size_t)(bm + lm) * G2_K + k0base + lk;
  const float* Bptr = B + (size_t)k0base * 256 + tid;

  float4 apre = *(const float4*)Aptr;
  float bpre[16];
#pragma unroll
  for (int r = 0; r < 16; r++) bpre[r] = Bptr[r * 256];

  const int NT = G2_KSLICE / 16;   // 50
  for (int kt = 0; kt < NT; kt++) {
    As[lk + 0][lm] = apre.x;
    As[lk + 1][lm] = apre.y;
    As[lk + 2][lm] = apre.z;
    As[lk + 3][lm] = apre.w;
#pragma unroll
    for (int r = 0; r < 16; r++) Bs[r][tid] = bpre[r];
    __syncthreads();

    if (kt + 1 < NT) {
      apre = *(const float4*)(Aptr + (kt + 1) * 16);
#pragma unroll
      for (int r = 0; r < 16; r++) bpre[r] = Bptr[((kt + 1) * 16 + r) * 256];
    }

#pragma unroll
    for (int kk = 0; kk < 16; kk++) {
      float a[8], bf[8];
#pragma unroll
      for (int i = 0; i < 8; i++) a[i] = As[kk][ty * 8 + i];
#pragma unroll
      for (int j = 0; j < 8; j++) bf[j] = Bs[kk][tx + 32 * j];
#pragma unroll
      for (int i = 0; i < 8; i++)
#pragma unroll
        for (int j = 0; j < 8; j++) acc[i][j] = fmaf(a[i], bf[j], acc[i][j]);
    }
    __syncthreads();
  }

  float* out = Cp + (size_t)blockIdx.y * N_GRAPHS * 256;
#pragma unroll
  for (int i = 0; i < 8; i++)
#pragma unroll
    for (int j = 0; j < 8; j++)
      out[(size_t)(bm + ty * 8 + i) * 256 + tx + 32 * j] = acc[i][j];
}

// split-K reduce + bias + relu
__global__ __launch_bounds__(256) void reduce_kernel(const float* __restrict__ Cp,
                                                     const float* __restrict__ bias,
                                                     float* __restrict__ out1) {
  int i = blockIdx.x * 256 + threadIdx.x;
  const size_t S = (size_t)N_GRAPHS * 256;
  float v = bias[i & 255];
#pragma unroll
  for (int s = 0; s < G2_SPLIT; s++) v += Cp[s * S + i];
  out1[i] = fmaxf(v, 0.f);
}

// ---------------------------------------------------------------- tail
__global__ __launch_bounds__(256) void tail_kernel(const float* __restrict__ out1,
                                                   const float* __restrict__ Wd2,
                                                   const float* __restrict__ bd2,
                                                   const float* __restrict__ Wd3,
                                                   const float* __restrict__ bd3,
                                                   float* __restrict__ out) {
  int lane = threadIdx.x & 63;
  int wave = threadIdx.x >> 6;
  int row = blockIdx.x * 4 + wave;

  const float* in = out1 + (size_t)row * 256;
  float i0 = in[lane];
  float i1 = in[64 + lane];
  float i2 = in[128 + lane];
  float i3 = in[192 + lane];

  float a0 = bd2[lane];
  float a1 = bd2[64 + lane];
#pragma unroll
  for (int i = 0; i < 64; i++) {
    float v0 = __shfl(i0, i);
    a0 = fmaf(v0, Wd2[(i)*128 + lane], a0);
    a1 = fmaf(v0, Wd2[(i)*128 + 64 + lane], a1);
    float v1 = __shfl(i1, i);
    a0 = fmaf(v1, Wd2[(64 + i) * 128 + lane], a0);
    a1 = fmaf(v1, Wd2[(64 + i) * 128 + 64 + lane], a1);
    float v2 = __shfl(i2, i);
    a0 = fmaf(v2, Wd2[(128 + i) * 128 + lane], a0);
    a1 = fmaf(v2, Wd2[(128 + i) * 128 + 64 + lane], a1);
    float v3 = __shfl(i3, i);
    a0 = fmaf(v3, Wd2[(192 + i) * 128 + lane], a0);
    a1 = fmaf(v3, Wd2[(192 + i) * 128 + 64 + lane], a1);
  }
  a0 = fmaxf(a0, 0.f);
  a1 = fmaxf(a1, 0.f);
  float p = a0 * Wd3[lane] + a1 * Wd3[64 + lane];
#pragma unroll
  for (int m = 32; m >= 1; m >>= 1) p += __shfl_xor(p, m);
  if (lane == 0) out[row] = 1.f / (1.f + expf(-(p + bd3[0])));
}

// ---------------------------------------------------------------- launcher
extern "C" void kernel_launch(void* const* d_in, const int* in_sizes, int n_in,
                              void* d_out, int out_size, void* d_ws, size_t ws_size,
                              hipStream_t stream) {
  const float* x        = (const float*)d_in[0];
  const int*   senders  = (const int*)d_in[1];
  const int*   receivers= (const int*)d_in[2];
  const float* W1       = (const float*)d_in[3];
  const float* b1       = (const float*)d_in[4];
  const float* gamma    = (const float*)d_in[5];
  const float* beta     = (const float*)d_in[6];
  const float* bn_mean  = (const float*)d_in[7];
  const float* bn_var   = (const float*)d_in[8];
  const float* W_d1     = (const float*)d_in[9];
  const float* b_d1     = (const float*)d_in[10];
  const float* W_d2     = (const float*)d_in[11];
  const float* b_d2     = (const float*)d_in[12];
  const float* W_d3     = (const float*)d_in[13];
  const float* b_d3     = (const float*)d_in[14];
  float* out = (float*)d_out;

  // workspace layout (aliasing: noff overlays wg_hist after partition1;
  // Cp+out1 overlay midrec+sorted after aggconv)
  char* ws = (char*)d_ws;
  float* h = (float*)ws;                 ws += (size_t)N_NODES * 64 * 4;       // 104.86 MB
  char* regB = ws;                       ws += (size_t)NPWG * NB1 * 4;         // 2.10 MB
  unsigned* wg_hist = (unsigned*)regB;
  unsigned* noff    = (unsigned*)regB;   // (N_NODES+1)*4 = 1.64 MB, fits
  unsigned* gtotal  = (unsigned*)ws;     ws += NB1 * 4;
  unsigned* gbase   = (unsigned*)ws;     ws += NB1 * 4;
  char* regDE = ws;                      // midrec(13.1MB) + sorted(13.1MB)
  unsigned short* midrec = (unsigned short*)regDE;
  unsigned short* sorted = (unsigned short*)(regDE + (size_t)N_EDGES * 2);
  float* Cp   = (float*)regDE;                                               // 33.55 MB
  float* out1 = (float*)(regDE + (size_t)G2_SPLIT * N_GRAPHS * 256 * 4);     // +4.19 MB

  count1_kernel<<<NPWG, 256, 0, stream>>>(receivers, wg_hist);
  scan_wg_kernel<<<NB1 / 256, 256, 0, stream>>>(wg_hist, gtotal);
  scan_bucket_kernel<<<1, 256, 0, stream>>>(gtotal, gbase);
  partition1_kernel<<<NPWG, 256, 0, stream>>>(receivers, senders, wg_hist, gbase, midrec);
  sort2_kernel<<<NB1, 256, 0, stream>>>(midrec, gtotal, gbase, sorted, noff);
  aggconv_kernel<<<N_GRAPHS, 256, 0, stream>>>(x, noff, sorted, W1, b1,
                                               gamma, beta, bn_mean, bn_var, h);
  gemm2_kernel<<<dim3(N_GRAPHS / 64, G2_SPLIT), 256, 0, stream>>>(h, W_d1, Cp);
  reduce_kernel<<<(N_GRAPHS * 256) / 256, 256, 0, stream>>>(Cp, b_d1, out1);
  tail_kernel<<<N_GRAPHS / 4, 256, 0, stream>>>(out1, W_d2, b_d2, W_d3, b_d3, out);
}

// Round 5
// 627.857 us; speedup vs baseline: 4.7056x; 1.2710x over previous
//
#include <hip/hip_runtime.h>
#include <cstdint>
#include <cstddef>

#define GRAPH_SIZE 100
#define N_GRAPHS 4096
#define N_NODES (N_GRAPHS * GRAPH_SIZE)   // 409600
#define DEG 16
#define N_EDGES (N_NODES * DEG)           // 6553600
#define BN_EPS 1e-3f

#define NB1 1024                  // level-1 buckets: 4 graphs / 400 nodes each
#define NPB 400                   // nodes per bucket
#define PCHUNK 12800              // edges per partition WG
#define NPWG (N_EDGES / PCHUNK)   // 512
#define BSTRIDE 8192              // padded per-bucket edge capacity (fixed stride)
#define ECAP 2304                 // per-graph staged edge capacity

// ---------------------------------------------------------------- count1
__global__ __launch_bounds__(256) void count1_kernel(const int* __restrict__ recv,
                                                     unsigned* __restrict__ wg_hist) {
  __shared__ unsigned lh[NB1];
  int tid = threadIdx.x, w = blockIdx.x;
  for (int i = tid; i < NB1; i += 256) lh[i] = 0;
  __syncthreads();
  size_t base = (size_t)w * PCHUNK;
  for (int i = tid; i < PCHUNK; i += 256)
    atomicAdd(&lh[(unsigned)recv[base + i] / NPB], 1u);
  __syncthreads();
  for (int i = tid; i < NB1; i += 256) wg_hist[(size_t)w * NB1 + i] = lh[i];
}

// ---------------------------------------------------------------- scans
__global__ __launch_bounds__(256) void scan_wg_kernel(unsigned* __restrict__ wg_hist,
                                                      unsigned* __restrict__ gtotal) {
  int b = blockIdx.x * 256 + threadIdx.x;   // grid = NB1/256 = 4
  unsigned run = 0;
  for (int w = 0; w < NPWG; w++) {
    size_t idx = (size_t)w * NB1 + b;
    unsigned c = wg_hist[idx];
    wg_hist[idx] = run;
    run += c;
  }
  gtotal[b] = run;
}

__global__ __launch_bounds__(256) void scan_bucket_kernel(const unsigned* __restrict__ gtotal,
                                                          unsigned* __restrict__ gbase) {
  __shared__ unsigned tmp[256];
  int tid = threadIdx.x;
  unsigned my[4], s4 = 0;
#pragma unroll
  for (int j = 0; j < 4; j++) { my[j] = gtotal[tid * 4 + j]; s4 += my[j]; }
  tmp[tid] = s4;
  __syncthreads();
  unsigned acc = s4;
  for (int d = 1; d < 256; d <<= 1) {
    unsigned t = (tid >= d) ? tmp[tid - d] : 0;
    __syncthreads();
    acc += t;
    tmp[tid] = acc;
    __syncthreads();
  }
  unsigned run = tmp[tid] - s4;
#pragma unroll
  for (int j = 0; j < 4; j++) { gbase[tid * 4 + j] = run; run += my[j]; }
}

// ---------------------------------------------------------------- partition1
// u16 record = gib(2b)<<14 | sl(7b)<<7 | rl(7b)
__global__ __launch_bounds__(256) void partition1_kernel(const int* __restrict__ recv,
                                                         const int* __restrict__ send,
                                                         const unsigned* __restrict__ wg_hist,
                                                         const unsigned* __restrict__ gbase,
                                                         unsigned short* __restrict__ midrec) {
  __shared__ unsigned cur[NB1];
  __shared__ unsigned tmp[256];
  __shared__ unsigned stage[PCHUNK];
  int tid = threadIdx.x, w = blockIdx.x;
  size_t base = (size_t)w * PCHUNK;

  for (int i = tid; i < NB1; i += 256) cur[i] = 0;
  __syncthreads();
  for (int i = tid; i < PCHUNK; i += 256)
    atomicAdd(&cur[(unsigned)recv[base + i] / NPB], 1u);
  __syncthreads();

  unsigned my[4], s4 = 0;
#pragma unroll
  for (int j = 0; j < 4; j++) { my[j] = cur[tid * 4 + j]; s4 += my[j]; }
  tmp[tid] = s4;
  __syncthreads();
  unsigned acc = s4;
  for (int d = 1; d < 256; d <<= 1) {
    unsigned t = (tid >= d) ? tmp[tid - d] : 0;
    __syncthreads();
    acc += t;
    tmp[tid] = acc;
    __syncthreads();
  }
  unsigned run = tmp[tid] - s4;
#pragma unroll
  for (int j = 0; j < 4; j++) { cur[tid * 4 + j] = run; run += my[j]; }
  __syncthreads();

  for (int i = tid; i < PCHUNK; i += 256) {
    unsigned r = (unsigned)recv[base + i];
    unsigned s = (unsigned)send[base + i];
    unsigned b = r / NPB;
    unsigned rin = r - b * NPB;
    unsigned gib = rin / 100;
    unsigned rl = rin - gib * 100;
    unsigned sl = s - (s / 100) * 100;
    unsigned pos = atomicAdd(&cur[b], 1u);
    stage[pos] = (b << 16) | (gib << 14) | (sl << 7) | rl;
  }
  __syncthreads();

  const unsigned* wrow = wg_hist + (size_t)w * NB1;
  for (int p = tid; p < PCHUNK; p += 256) {
    unsigned rec = stage[p];
    unsigned b = rec >> 16;
    unsigned start = (b > 0) ? cur[b - 1] : 0;
    unsigned dest = gbase[b] + wrow[b] + ((unsigned)p - start);
    midrec[dest] = (unsigned short)(rec & 0xFFFFu);
  }
}

// ---------------------------------------------------------------- sort2
// Per-bucket LDS sort by receiver node with PADDING: each node's edge list is
// padded to a multiple of 4 with sentinel records pointing at the zero row
// (word offset 100*64=6400). Output record = sl*64 (pre-multiplied LDS word
// offset). Fixed per-bucket output stride BSTRIDE. noff[b*401+k] absolute.
__global__ __launch_bounds__(256) void sort2_kernel(const unsigned short* __restrict__ midrec,
                                                    const unsigned* __restrict__ gtotal,
                                                    const unsigned* __restrict__ gbase,
                                                    unsigned short* __restrict__ sorted,
                                                    unsigned* __restrict__ noff) {
  __shared__ unsigned short smid[BSTRIDE];
  __shared__ unsigned short dst[BSTRIDE];
  __shared__ unsigned hist[512];
  __shared__ unsigned tmp[256];
  __shared__ unsigned s_ptot;
  int tid = threadIdx.x, b = blockIdx.x;
  unsigned cnt = gtotal[b];
  if (cnt > BSTRIDE) cnt = BSTRIDE;
  unsigned gb = gbase[b];

  for (unsigned i = tid; i < cnt; i += 256) smid[i] = midrec[gb + i];
  hist[tid] = 0; hist[256 + tid] = 0;
  {
    unsigned* d32 = (unsigned*)dst;
    for (int i = tid; i < BSTRIDE / 2; i += 256) d32[i] = 0x19001900u;  // 6400|6400
  }
  __syncthreads();

  for (unsigned i = tid; i < cnt; i += 256) {
    unsigned rec = smid[i];
    unsigned nib = (rec >> 14) * 100 + (rec & 127u);
    atomicAdd(&hist[nib], 1u);
  }
  __syncthreads();

  unsigned c0 = hist[2 * tid], c1 = hist[2 * tid + 1];
  unsigned p0 = (c0 + 3u) & ~3u, p1 = (c1 + 3u) & ~3u;
  unsigned s2 = p0 + p1;
  tmp[tid] = s2;
  __syncthreads();
  unsigned acc = s2;
  for (int d = 1; d < 256; d <<= 1) {
    unsigned t = (tid >= d) ? tmp[tid - d] : 0;
    __syncthreads();
    acc += t;
    tmp[tid] = acc;
    __syncthreads();
  }
  unsigned pb0 = acc - s2;
  unsigned pb1 = pb0 + p0;
  unsigned obase = (unsigned)b * BSTRIDE;
  int k0 = 2 * tid, k1 = 2 * tid + 1;
  if (k0 <= NPB) noff[(size_t)b * 401 + k0] = obase + pb0;
  if (k1 <= NPB) noff[(size_t)b * 401 + k1] = obase + pb1;
  if (k0 == NPB) s_ptot = pb0;     // counts for k>=400 are all 0
  __syncthreads();
  hist[k0] = pb0;                  // cursors (counts no longer needed)
  hist[k1] = pb1;
  __syncthreads();

  for (unsigned i = tid; i < cnt; i += 256) {
    unsigned rec = smid[i];
    unsigned nib = (rec >> 14) * 100 + (rec & 127u);
    unsigned pos = atomicAdd(&hist[nib], 1u);
    if (pos < BSTRIDE) dst[pos] = (unsigned short)(((rec >> 7) & 127u) * 64u);
  }
  __syncthreads();

  unsigned ptot = s_ptot;
  if (ptot > BSTRIDE) ptot = BSTRIDE;
  unsigned* o32 = (unsigned*)sorted + (size_t)b * (BSTRIDE / 2);
  unsigned* d32 = (unsigned*)dst;
  for (unsigned i = tid; i < (ptot >> 1); i += 256) o32[i] = d32[i];
}

// --------------------------------------------- fused aggregate+conv+BN+ELU
// One WG per graph, 30.9 KB LDS (5 WG/CU). Phase 2 accumulators in VGPRs
// (static unroll), xs buffer reused for the agg rows after a barrier.
__global__ __launch_bounds__(256) void aggconv_kernel(
    const float* __restrict__ x, const unsigned* __restrict__ noff,
    const unsigned short* __restrict__ sorted,
    const float* __restrict__ W1, const float* __restrict__ b1,
    const float* __restrict__ gamma, const float* __restrict__ beta,
    const float* __restrict__ bn_mean, const float* __restrict__ bn_var,
    float* __restrict__ h) {
  __shared__ float xs[6464];              // rows 0..99 = x block, row 100 = zeros
  __shared__ unsigned short es[ECAP];     // graph's padded edge records (sl*64)
  __shared__ unsigned nof[104];           // local CSR offsets (node 0..100)
  int tid = threadIdx.x, lane = tid & 63, wv = tid >> 6;
  int g = blockIdx.x;
  size_t gb64 = (size_t)g * 6400;

  const float4* xsrc = (const float4*)(x + gb64);
  float4* xd = (float4*)xs;
  for (int i = tid; i < 1600; i += 256) xd[i] = xsrc[i];
  if (tid < 64) xs[6400 + tid] = 0.f;

  int b = g >> 2, gib = g & 3;
  size_t base401 = (size_t)b * 401 + (size_t)gib * 100;
  unsigned gbeg = noff[base401];
  unsigned gend = noff[base401 + 100];
  unsigned ecnt = gend - gbeg;
  if (ecnt > ECAP) ecnt = ECAP;
  if (tid <= 100) nof[tid] = noff[base401 + tid] - gbeg;
  {
    const unsigned* s32 = (const unsigned*)sorted + (gbeg >> 1);
    unsigned* e32 = (unsigned*)es;
    for (unsigned i = tid; i < (ecnt >> 1); i += 256) e32[i] = s32[i];
  }
  __syncthreads();

  // phase 2: branchless padded aggregation, accs in registers
  float accs[25];
#pragma unroll
  for (int J = 0; J < 25; J++) {
    int n = wv + 4 * J;
    unsigned e = nof[n], e1 = nof[n + 1];
    float acc = 0.f;
    for (; e < e1; e += 4) {
      unsigned long long v = *(const unsigned long long*)&es[e];
      acc += xs[((unsigned)v & 0xFFFFu) + lane];
      acc += xs[((unsigned)(v >> 16) & 0xFFFFu) + lane];
      acc += xs[((unsigned)(v >> 32) & 0xFFFFu) + lane];
      acc += xs[(unsigned)(v >> 48) + lane];
    }
    accs[J] = acc;
  }
  __syncthreads();   // all xs reads done -> safe to overwrite
#pragma unroll
  for (int J = 0; J < 25; J++) xs[(wv + 4 * J) * 64 + lane] = accs[J];
  __syncthreads();

  // phase 3: conv (matvec via uniform LDS broadcast) + BN + ELU
  float w[64];
#pragma unroll
  for (int i = 0; i < 64; i++) w[i] = W1[i * 64 + lane];
  float scale = gamma[lane] * rsqrtf(bn_var[lane] + BN_EPS);
  float mb = bn_mean[lane], bt = beta[lane], bias1 = b1[lane];

#pragma unroll
  for (int J = 0; J < 25; J++) {
    int n = wv + 4 * J;
    float hv = bias1;
#pragma unroll
    for (int q = 0; q < 16; q++) {
      float4 av = *(const float4*)&xs[n * 64 + q * 4];
      hv = fmaf(av.x, w[q * 4 + 0], hv);
      hv = fmaf(av.y, w[q * 4 + 1], hv);
      hv = fmaf(av.z, w[q * 4 + 2], hv);
      hv = fmaf(av.w, w[q * 4 + 3], hv);
    }
    hv = (hv - mb) * scale + bt;
    hv = (hv > 0.f) ? hv : expm1f(hv);
    h[gb64 + (size_t)n * 64 + lane] = hv;
  }
}

// ---------------------------------------------------------------- GEMM2
#define G2_K 6400
#define G2_SPLIT 8
#define G2_KSLICE (G2_K / G2_SPLIT)   // 800
__global__ __launch_bounds__(256) void gemm2_kernel(const float* __restrict__ A,
                                                    const float* __restrict__ B,
                                                    float* __restrict__ Cp) {
  __shared__ float As[16][68];
  __shared__ float Bs[16][256];
  int tid = threadIdx.x;
  int tx = tid & 31;
  int ty = tid >> 5;
  int bm = blockIdx.x * 64;
  int k0base = blockIdx.y * G2_KSLICE;

  float acc[8][8] = {};

  int lm = tid >> 2;
  int lk = (tid & 3) * 4;
  const float* Aptr = A + (size_t)(bm + lm) * G2_K + k0base + lk;
  const float* Bptr = B + (size_t)k0base * 256 + tid;

  float4 apre = *(const float4*)Aptr;
  float bpre[16];
#pragma unroll
  for (int r = 0; r < 16; r++) bpre[r] = Bptr[r * 256];

  const int NT = G2_KSLICE / 16;   // 50
  for (int kt = 0; kt < NT; kt++) {
    As[lk + 0][lm] = apre.x;
    As[lk + 1][lm] = apre.y;
    As[lk + 2][lm] = apre.z;
    As[lk + 3][lm] = apre.w;
#pragma unroll
    for (int r = 0; r < 16; r++) Bs[r][tid] = bpre[r];
    __syncthreads();

    if (kt + 1 < NT) {
      apre = *(const float4*)(Aptr + (kt + 1) * 16);
#pragma unroll
      for (int r = 0; r < 16; r++) bpre[r] = Bptr[((kt + 1) * 16 + r) * 256];
    }

#pragma unroll
    for (int kk = 0; kk < 16; kk++) {
      float4 aa = *(const float4*)&As[kk][ty * 8];
      float4 ab = *(const float4*)&As[kk][ty * 8 + 4];
      float a[8] = {aa.x, aa.y, aa.z, aa.w, ab.x, ab.y, ab.z, ab.w};
      float bf[8];
#pragma unroll
      for (int j = 0; j < 8; j++) bf[j] = Bs[kk][tx + 32 * j];
#pragma unroll
      for (int i = 0; i < 8; i++)
#pragma unroll
        for (int j = 0; j < 8; j++) acc[i][j] = fmaf(a[i], bf[j], acc[i][j]);
    }
    __syncthreads();
  }

  float* out = Cp + (size_t)blockIdx.y * N_GRAPHS * 256;
#pragma unroll
  for (int i = 0; i < 8; i++)
#pragma unroll
    for (int j = 0; j < 8; j++)
      out[(size_t)(bm + ty * 8 + i) * 256 + tx + 32 * j] = acc[i][j];
}

__global__ __launch_bounds__(256) void reduce_kernel(const float* __restrict__ Cp,
                                                     const float* __restrict__ bias,
                                                     float* __restrict__ out1) {
  int i = blockIdx.x * 256 + threadIdx.x;
  const size_t S = (size_t)N_GRAPHS * 256;
  float v = bias[i & 255];
#pragma unroll
  for (int s = 0; s < G2_SPLIT; s++) v += Cp[s * S + i];
  out1[i] = fmaxf(v, 0.f);
}

// ---------------------------------------------------------------- tail
__global__ __launch_bounds__(256) void tail_kernel(const float* __restrict__ out1,
                                                   const float* __restrict__ Wd2,
                                                   const float* __restrict__ bd2,
                                                   const float* __restrict__ Wd3,
                                                   const float* __restrict__ bd3,
                                                   float* __restrict__ out) {
  int lane = threadIdx.x & 63;
  int wave = threadIdx.x >> 6;
  int row = blockIdx.x * 4 + wave;

  const float* in = out1 + (size_t)row * 256;
  float i0 = in[lane];
  float i1 = in[64 + lane];
  float i2 = in[128 + lane];
  float i3 = in[192 + lane];

  float a0 = bd2[lane];
  float a1 = bd2[64 + lane];
#pragma unroll
  for (int i = 0; i < 64; i++) {
    float v0 = __shfl(i0, i);
    a0 = fmaf(v0, Wd2[(i)*128 + lane], a0);
    a1 = fmaf(v0, Wd2[(i)*128 + 64 + lane], a1);
    float v1 = __shfl(i1, i);
    a0 = fmaf(v1, Wd2[(64 + i) * 128 + lane], a0);
    a1 = fmaf(v1, Wd2[(64 + i) * 128 + 64 + lane], a1);
    float v2 = __shfl(i2, i);
    a0 = fmaf(v2, Wd2[(128 + i) * 128 + lane], a0);
    a1 = fmaf(v2, Wd2[(128 + i) * 128 + 64 + lane], a1);
    float v3 = __shfl(i3, i);
    a0 = fmaf(v3, Wd2[(192 + i) * 128 + lane], a0);
    a1 = fmaf(v3, Wd2[(192 + i) * 128 + 64 + lane], a1);
  }
  a0 = fmaxf(a0, 0.f);
  a1 = fmaxf(a1, 0.f);
  float p = a0 * Wd3[lane] + a1 * Wd3[64 + lane];
#pragma unroll
  for (int m = 32; m >= 1; m >>= 1) p += __shfl_xor(p, m);
  if (lane == 0) out[row] = 1.f / (1.f + expf(-(p + bd3[0])));
}

// ---------------------------------------------------------------- launcher
extern "C" void kernel_launch(void* const* d_in, const int* in_sizes, int n_in,
                              void* d_out, int out_size, void* d_ws, size_t ws_size,
                              hipStream_t stream) {
  const float* x        = (const float*)d_in[0];
  const int*   senders  = (const int*)d_in[1];
  const int*   receivers= (const int*)d_in[2];
  const float* W1       = (const float*)d_in[3];
  const float* b1       = (const float*)d_in[4];
  const float* gamma    = (const float*)d_in[5];
  const float* beta     = (const float*)d_in[6];
  const float* bn_mean  = (const float*)d_in[7];
  const float* bn_var   = (const float*)d_in[8];
  const float* W_d1     = (const float*)d_in[9];
  const float* b_d1     = (const float*)d_in[10];
  const float* W_d2     = (const float*)d_in[11];
  const float* b_d2     = (const float*)d_in[12];
  const float* W_d3     = (const float*)d_in[13];
  const float* b_d3     = (const float*)d_in[14];
  float* out = (float*)d_out;

  // workspace layout
  char* ws = (char*)d_ws;
  float* h = (float*)ws;                 ws += (size_t)N_NODES * 64 * 4;       // 104.86 MB
  char* regB = ws;                       ws += (size_t)NPWG * NB1 * 4;         // 2.10 MB
  unsigned* wg_hist = (unsigned*)regB;
  unsigned* noff    = (unsigned*)regB;   // NB1*401*4 = 1.64 MB (after partition1)
  unsigned* gtotal  = (unsigned*)ws;     ws += NB1 * 4;
  unsigned* gbase   = (unsigned*)ws;     ws += NB1 * 4;
  char* regDE = ws;   // midrec(13.1MB)+sorted(16.8MB) -> later Cp(33.6)+out1(4.2)
  unsigned short* midrec = (unsigned short*)regDE;
  unsigned short* sorted = (unsigned short*)(regDE + (size_t)N_EDGES * 2);
  float* Cp   = (float*)regDE;
  float* out1 = (float*)(regDE + (size_t)G2_SPLIT * N_GRAPHS * 256 * 4);

  count1_kernel<<<NPWG, 256, 0, stream>>>(receivers, wg_hist);
  scan_wg_kernel<<<NB1 / 256, 256, 0, stream>>>(wg_hist, gtotal);
  scan_bucket_kernel<<<1, 256, 0, stream>>>(gtotal, gbase);
  partition1_kernel<<<NPWG, 256, 0, stream>>>(receivers, senders, wg_hist, gbase, midrec);
  sort2_kernel<<<NB1, 256, 0, stream>>>(midrec, gtotal, gbase, sorted, noff);
  aggconv_kernel<<<N_GRAPHS, 256, 0, stream>>>(x, noff, sorted, W1, b1,
                                               gamma, beta, bn_mean, bn_var, h);
  gemm2_kernel<<<dim3(N_GRAPHS / 64, G2_SPLIT), 256, 0, stream>>>(h, W_d1, Cp);
  reduce_kernel<<<(N_GRAPHS * 256) / 256, 256, 0, stream>>>(Cp, b_d1, out1);
  tail_kernel<<<N_GRAPHS / 4, 256, 0, stream>>>(out1, W_d2, b_d2, W_d3, b_d3, out);
}

// Round 6
// 514.435 us; speedup vs baseline: 5.7430x; 1.2205x over previous
//
#include <hip/hip_runtime.h>
#include <cstdint>
#include <cstddef>

#define GRAPH_SIZE 100
#define N_GRAPHS 4096
#define N_NODES (N_GRAPHS * GRAPH_SIZE)   // 409600
#define DEG 16
#define N_EDGES (N_NODES * DEG)           // 6553600
#define BN_EPS 1e-3f

#define NB1 1024                  // level-1 buckets: 4 graphs / 400 nodes each
#define NPB 400                   // nodes per bucket
#define PCHUNK 12800              // edges per partition WG
#define NPWG (N_EDGES / PCHUNK)   // 512
#define BSTRIDE 8192              // padded per-bucket edge capacity (fixed stride)
#define ECAP 2304                 // per-graph staged edge capacity

typedef __attribute__((ext_vector_type(8))) unsigned short ushort8;
typedef __attribute__((ext_vector_type(8))) short short8;
typedef __attribute__((ext_vector_type(4))) float f32x4;

__device__ __forceinline__ unsigned f2bf(float f) {   // RNE float->bf16 bits
  unsigned u = __float_as_uint(f);
  return (u + 0x7FFFu + ((u >> 16) & 1u)) >> 16;
}
__device__ __forceinline__ float bf2f(unsigned h) {
  return __uint_as_float(h << 16);
}

// ---------------------------------------------------------------- count1
__global__ __launch_bounds__(256) void count1_kernel(const int* __restrict__ recv,
                                                     unsigned* __restrict__ wg_hist) {
  __shared__ unsigned lh[NB1];
  int tid = threadIdx.x, w = blockIdx.x;
  for (int i = tid; i < NB1; i += 256) lh[i] = 0;
  __syncthreads();
  size_t base = (size_t)w * PCHUNK;
  for (int i = tid; i < PCHUNK; i += 256)
    atomicAdd(&lh[(unsigned)recv[base + i] / NPB], 1u);
  __syncthreads();
  for (int i = tid; i < NB1; i += 256) wg_hist[(size_t)w * NB1 + i] = lh[i];
}

// ---------------------------------------------------------------- scans
__global__ __launch_bounds__(256) void scan_wg_kernel(unsigned* __restrict__ wg_hist,
                                                      unsigned* __restrict__ gtotal) {
  int b = blockIdx.x * 256 + threadIdx.x;   // grid = NB1/256 = 4
  unsigned run = 0;
  for (int w = 0; w < NPWG; w++) {
    size_t idx = (size_t)w * NB1 + b;
    unsigned c = wg_hist[idx];
    wg_hist[idx] = run;
    run += c;
  }
  gtotal[b] = run;
}

__global__ __launch_bounds__(256) void scan_bucket_kernel(const unsigned* __restrict__ gtotal,
                                                          unsigned* __restrict__ gbase) {
  __shared__ unsigned tmp[256];
  int tid = threadIdx.x;
  unsigned my[4], s4 = 0;
#pragma unroll
  for (int j = 0; j < 4; j++) { my[j] = gtotal[tid * 4 + j]; s4 += my[j]; }
  tmp[tid] = s4;
  __syncthreads();
  unsigned acc = s4;
  for (int d = 1; d < 256; d <<= 1) {
    unsigned t = (tid >= d) ? tmp[tid - d] : 0;
    __syncthreads();
    acc += t;
    tmp[tid] = acc;
    __syncthreads();
  }
  unsigned run = tmp[tid] - s4;
#pragma unroll
  for (int j = 0; j < 4; j++) { gbase[tid * 4 + j] = run; run += my[j]; }
}

// ---------------------------------------------------------------- partition1
// u16 record = gib(2b)<<14 | sl(7b)<<7 | rl(7b)
__global__ __launch_bounds__(256) void partition1_kernel(const int* __restrict__ recv,
                                                         const int* __restrict__ send,
                                                         const unsigned* __restrict__ wg_hist,
                                                         const unsigned* __restrict__ gbase,
                                                         unsigned short* __restrict__ midrec) {
  __shared__ unsigned cur[NB1];
  __shared__ unsigned tmp[256];
  __shared__ unsigned stage[PCHUNK];
  int tid = threadIdx.x, w = blockIdx.x;
  size_t base = (size_t)w * PCHUNK;

  for (int i = tid; i < NB1; i += 256) cur[i] = 0;
  __syncthreads();
  for (int i = tid; i < PCHUNK; i += 256)
    atomicAdd(&cur[(unsigned)recv[base + i] / NPB], 1u);
  __syncthreads();

  unsigned my[4], s4 = 0;
#pragma unroll
  for (int j = 0; j < 4; j++) { my[j] = cur[tid * 4 + j]; s4 += my[j]; }
  tmp[tid] = s4;
  __syncthreads();
  unsigned acc = s4;
  for (int d = 1; d < 256; d <<= 1) {
    unsigned t = (tid >= d) ? tmp[tid - d] : 0;
    __syncthreads();
    acc += t;
    tmp[tid] = acc;
    __syncthreads();
  }
  unsigned run = tmp[tid] - s4;
#pragma unroll
  for (int j = 0; j < 4; j++) { cur[tid * 4 + j] = run; run += my[j]; }
  __syncthreads();

  for (int i = tid; i < PCHUNK; i += 256) {
    unsigned r = (unsigned)recv[base + i];
    unsigned s = (unsigned)send[base + i];
    unsigned b = r / NPB;
    unsigned rin = r - b * NPB;
    unsigned gib = rin / 100;
    unsigned rl = rin - gib * 100;
    unsigned sl = s - (s / 100) * 100;
    unsigned pos = atomicAdd(&cur[b], 1u);
    stage[pos] = (b << 16) | (gib << 14) | (sl << 7) | rl;
  }
  __syncthreads();

  const unsigned* wrow = wg_hist + (size_t)w * NB1;
  for (int p = tid; p < PCHUNK; p += 256) {
    unsigned rec = stage[p];
    unsigned b = rec >> 16;
    unsigned start = (b > 0) ? cur[b - 1] : 0;
    unsigned dest = gbase[b] + wrow[b] + ((unsigned)p - start);
    midrec[dest] = (unsigned short)(rec & 0xFFFFu);
  }
}

// ---------------------------------------------------------------- sort2
// Per-bucket LDS sort by receiver node with PADDING to x4 (sentinel = zero
// row word offset 6400). Output record = sl*64. Fixed stride BSTRIDE.
__global__ __launch_bounds__(256) void sort2_kernel(const unsigned short* __restrict__ midrec,
                                                    const unsigned* __restrict__ gtotal,
                                                    const unsigned* __restrict__ gbase,
                                                    unsigned short* __restrict__ sorted,
                                                    unsigned* __restrict__ noff) {
  __shared__ unsigned short smid[BSTRIDE];
  __shared__ unsigned short dst[BSTRIDE];
  __shared__ unsigned hist[512];
  __shared__ unsigned tmp[256];
  __shared__ unsigned s_ptot;
  int tid = threadIdx.x, b = blockIdx.x;
  unsigned cnt = gtotal[b];
  if (cnt > BSTRIDE) cnt = BSTRIDE;
  unsigned gb = gbase[b];

  for (unsigned i = tid; i < cnt; i += 256) smid[i] = midrec[gb + i];
  hist[tid] = 0; hist[256 + tid] = 0;
  {
    unsigned* d32 = (unsigned*)dst;
    for (int i = tid; i < BSTRIDE / 2; i += 256) d32[i] = 0x19001900u;  // 6400|6400
  }
  __syncthreads();

  for (unsigned i = tid; i < cnt; i += 256) {
    unsigned rec = smid[i];
    unsigned nib = (rec >> 14) * 100 + (rec & 127u);
    atomicAdd(&hist[nib], 1u);
  }
  __syncthreads();

  unsigned c0 = hist[2 * tid], c1 = hist[2 * tid + 1];
  unsigned p0 = (c0 + 3u) & ~3u, p1 = (c1 + 3u) & ~3u;
  unsigned s2 = p0 + p1;
  tmp[tid] = s2;
  __syncthreads();
  unsigned acc = s2;
  for (int d = 1; d < 256; d <<= 1) {
    unsigned t = (tid >= d) ? tmp[tid - d] : 0;
    __syncthreads();
    acc += t;
    tmp[tid] = acc;
    __syncthreads();
  }
  unsigned pb0 = acc - s2;
  unsigned pb1 = pb0 + p0;
  unsigned obase = (unsigned)b * BSTRIDE;
  int k0 = 2 * tid, k1 = 2 * tid + 1;
  if (k0 <= NPB) noff[(size_t)b * 401 + k0] = obase + pb0;
  if (k1 <= NPB) noff[(size_t)b * 401 + k1] = obase + pb1;
  if (k0 == NPB) s_ptot = pb0;
  __syncthreads();
  hist[k0] = pb0;
  hist[k1] = pb1;
  __syncthreads();

  for (unsigned i = tid; i < cnt; i += 256) {
    unsigned rec = smid[i];
    unsigned nib = (rec >> 14) * 100 + (rec & 127u);
    unsigned pos = atomicAdd(&hist[nib], 1u);
    if (pos < BSTRIDE) dst[pos] = (unsigned short)(((rec >> 7) & 127u) * 64u);
  }
  __syncthreads();

  unsigned ptot = s_ptot;
  if (ptot > BSTRIDE) ptot = BSTRIDE;
  unsigned* o32 = (unsigned*)sorted + (size_t)b * (BSTRIDE / 2);
  unsigned* d32 = (unsigned*)dst;
  for (unsigned i = tid; i < (ptot >> 1); i += 256) o32[i] = d32[i];
}

// --------------------------------------------- fused aggregate+conv+BN+ELU
// One WG per graph. Epilogue writes h as bf16 hi/lo planes for the MFMA GEMM.
__global__ __launch_bounds__(256) void aggconv_kernel(
    const float* __restrict__ x, const unsigned* __restrict__ noff,
    const unsigned short* __restrict__ sorted,
    const float* __restrict__ W1, const float* __restrict__ b1,
    const float* __restrict__ gamma, const float* __restrict__ beta,
    const float* __restrict__ bn_mean, const float* __restrict__ bn_var,
    unsigned short* __restrict__ h_hi, unsigned short* __restrict__ h_lo) {
  __shared__ float xs[6464];              // rows 0..99 = x block, row 100 = zeros
  __shared__ unsigned short es[ECAP];     // graph's padded edge records (sl*64)
  __shared__ unsigned nof[104];           // local CSR offsets (node 0..100)
  int tid = threadIdx.x, lane = tid & 63, wv = tid >> 6;
  int g = blockIdx.x;
  size_t gb64 = (size_t)g * 6400;

  const float4* xsrc = (const float4*)(x + gb64);
  float4* xd = (float4*)xs;
  for (int i = tid; i < 1600; i += 256) xd[i] = xsrc[i];
  if (tid < 64) xs[6400 + tid] = 0.f;

  int b = g >> 2, gib = g & 3;
  size_t base401 = (size_t)b * 401 + (size_t)gib * 100;
  unsigned gbeg = noff[base401];
  unsigned gend = noff[base401 + 100];
  unsigned ecnt = gend - gbeg;
  if (ecnt > ECAP) ecnt = ECAP;
  if (tid <= 100) nof[tid] = noff[base401 + tid] - gbeg;
  {
    const unsigned* s32 = (const unsigned*)sorted + (gbeg >> 1);
    unsigned* e32 = (unsigned*)es;
    for (unsigned i = tid; i < (ecnt >> 1); i += 256) e32[i] = s32[i];
  }
  __syncthreads();

  float accs[25];
#pragma unroll
  for (int J = 0; J < 25; J++) {
    int n = wv + 4 * J;
    unsigned e = nof[n], e1 = nof[n + 1];
    float acc = 0.f;
    for (; e < e1; e += 4) {
      unsigned long long v = *(const unsigned long long*)&es[e];
      acc += xs[((unsigned)v & 0xFFFFu) + lane];
      acc += xs[((unsigned)(v >> 16) & 0xFFFFu) + lane];
      acc += xs[((unsigned)(v >> 32) & 0xFFFFu) + lane];
      acc += xs[(unsigned)(v >> 48) + lane];
    }
    accs[J] = acc;
  }
  __syncthreads();
#pragma unroll
  for (int J = 0; J < 25; J++) xs[(wv + 4 * J) * 64 + lane] = accs[J];
  __syncthreads();

  float w[64];
#pragma unroll
  for (int i = 0; i < 64; i++) w[i] = W1[i * 64 + lane];
  float scale = gamma[lane] * rsqrtf(bn_var[lane] + BN_EPS);
  float mb = bn_mean[lane], bt = beta[lane], bias1 = b1[lane];

#pragma unroll
  for (int J = 0; J < 25; J++) {
    int n = wv + 4 * J;
    float hv = bias1;
#pragma unroll
    for (int q = 0; q < 16; q++) {
      float4 av = *(const float4*)&xs[n * 64 + q * 4];
      hv = fmaf(av.x, w[q * 4 + 0], hv);
      hv = fmaf(av.y, w[q * 4 + 1], hv);
      hv = fmaf(av.z, w[q * 4 + 2], hv);
      hv = fmaf(av.w, w[q * 4 + 3], hv);
    }
    hv = (hv - mb) * scale + bt;
    hv = (hv > 0.f) ? hv : expm1f(hv);
    unsigned hi = f2bf(hv);
    unsigned lo = f2bf(hv - bf2f(hi));
    size_t idx = gb64 + (size_t)n * 64 + lane;
    h_hi[idx] = (unsigned short)hi;
    h_lo[idx] = (unsigned short)lo;
  }
}

// ---------------------------------------------------------------- W_d1 cvt
// W[6400][256] f32 -> Bt_hi/Bt_lo[256][6400] bf16 (transposed planes)
__global__ __launch_bounds__(256) void wcvt_kernel(const float* __restrict__ W,
                                                   unsigned short* __restrict__ Bhi,
                                                   unsigned short* __restrict__ Blo) {
  __shared__ float sm[64][65];
  int tid = threadIdx.x;
  int k0 = blockIdx.x * 64;    // 100
  int n0 = blockIdx.y * 64;    // 4
  for (int i = tid; i < 1024; i += 256) {
    int r = i >> 4, c4 = i & 15;
    float4 v = *(const float4*)&W[(size_t)(k0 + r) * 256 + n0 + c4 * 4];
    sm[r][c4 * 4 + 0] = v.x; sm[r][c4 * 4 + 1] = v.y;
    sm[r][c4 * 4 + 2] = v.z; sm[r][c4 * 4 + 3] = v.w;
  }
  __syncthreads();
  for (int i = tid; i < 512; i += 256) {
    int nn = i >> 3, kk = i & 7;
    ushort8 hi, lo;
#pragma unroll
    for (int j = 0; j < 8; j++) {
      float f = sm[kk * 8 + j][nn];
      unsigned hb = f2bf(f);
      hi[j] = (unsigned short)hb;
      lo[j] = (unsigned short)f2bf(f - bf2f(hb));
    }
    size_t o = (size_t)(n0 + nn) * 6400 + k0 + kk * 8;
    *(ushort8*)&Bhi[o] = hi;
    *(ushort8*)&Blo[o] = lo;
  }
}

// ---------------------------------------------------------------- GEMM2 (MFMA)
// Cp[z][4096][256] += split-K partials of A[4096,6400] @ B[6400,256] where
// A = Ahi+Alo, B = Bhi+Blo (bf16 planes); 3-product split-bf16, fp32 acc.
// BM=64, BN=256, 4 waves each 64(M)x64(N) via 4x4 16x16x32 frags.
#define G2_SPLIT 8
#define G2_KSLICE 800
#define G2_STEPS (G2_KSLICE / 32)   // 25
__global__ __launch_bounds__(256) void gemm2_kernel(const unsigned short* __restrict__ Ahi,
                                                    const unsigned short* __restrict__ Alo,
                                                    const unsigned short* __restrict__ Bhi,
                                                    const unsigned short* __restrict__ Blo,
                                                    float* __restrict__ Cp) {
  __shared__ __align__(16) unsigned short As[2][64 * 40];    // row stride 80B
  __shared__ __align__(16) unsigned short Bs[2][256 * 40];
  int tid = threadIdx.x;
  int w = tid >> 6, l = tid & 63;
  int bm = blockIdx.x * 64;
  int kslice = blockIdx.y * G2_KSLICE;

  f32x4 acc[4][4];
#pragma unroll
  for (int i = 0; i < 4; i++)
#pragma unroll
    for (int j = 0; j < 4; j++) acc[i][j] = (f32x4){0.f, 0.f, 0.f, 0.f};

  int arow = tid >> 2, akg = tid & 3;
  const size_t abase = (size_t)(bm + arow) * 6400 + kslice + akg * 8;

  ushort8 pa_hi, pa_lo, pb_hi[4], pb_lo[4];
  pa_hi = *(const ushort8*)&Ahi[abase];
  pa_lo = *(const ushort8*)&Alo[abase];
#pragma unroll
  for (int i = 0; i < 4; i++) {
    int u = tid + 256 * i;
    size_t bb = (size_t)(u >> 2) * 6400 + kslice + (u & 3) * 8;
    pb_hi[i] = *(const ushort8*)&Bhi[bb];
    pb_lo[i] = *(const ushort8*)&Blo[bb];
  }

  for (int step = 0; step < G2_STEPS; step++) {
    __syncthreads();
    *(ushort8*)&As[0][arow * 40 + akg * 8] = pa_hi;
    *(ushort8*)&As[1][arow * 40 + akg * 8] = pa_lo;
#pragma unroll
    for (int i = 0; i < 4; i++) {
      int u = tid + 256 * i;
      *(ushort8*)&Bs[0][(u >> 2) * 40 + (u & 3) * 8] = pb_hi[i];
      *(ushort8*)&Bs[1][(u >> 2) * 40 + (u & 3) * 8] = pb_lo[i];
    }
    __syncthreads();

    if (step + 1 < G2_STEPS) {
      size_t koff = (size_t)(step + 1) * 32;
      pa_hi = *(const ushort8*)&Ahi[abase + koff];
      pa_lo = *(const ushort8*)&Alo[abase + koff];
#pragma unroll
      for (int i = 0; i < 4; i++) {
        int u = tid + 256 * i;
        size_t bb = (size_t)(u >> 2) * 6400 + kslice + (u & 3) * 8 + koff;
        pb_hi[i] = *(const ushort8*)&Bhi[bb];
        pb_lo[i] = *(const ushort8*)&Blo[bb];
      }
    }

    int kg8 = (l >> 4) * 8;
    short8 a_hi[4], a_lo[4];
#pragma unroll
    for (int mf = 0; mf < 4; mf++) {
      int r = mf * 16 + (l & 15);
      a_hi[mf] = *(const short8*)&As[0][r * 40 + kg8];
      a_lo[mf] = *(const short8*)&As[1][r * 40 + kg8];
    }
#pragma unroll
    for (int nf = 0; nf < 4; nf++) {
      int c = w * 64 + nf * 16 + (l & 15);
      short8 b_hi = *(const short8*)&Bs[0][c * 40 + kg8];
      short8 b_lo = *(const short8*)&Bs[1][c * 40 + kg8];
#pragma unroll
      for (int mf = 0; mf < 4; mf++) {
        acc[mf][nf] = __builtin_amdgcn_mfma_f32_16x16x32_bf16(a_hi[mf], b_hi, acc[mf][nf], 0, 0, 0);
        acc[mf][nf] = __builtin_amdgcn_mfma_f32_16x16x32_bf16(a_hi[mf], b_lo, acc[mf][nf], 0, 0, 0);
        acc[mf][nf] = __builtin_amdgcn_mfma_f32_16x16x32_bf16(a_lo[mf], b_hi, acc[mf][nf], 0, 0, 0);
      }
    }
  }

  float* outp = Cp + (size_t)blockIdx.y * N_GRAPHS * 256;
#pragma unroll
  for (int mf = 0; mf < 4; mf++)
#pragma unroll
    for (int nf = 0; nf < 4; nf++)
#pragma unroll
      for (int r = 0; r < 4; r++)
        outp[(size_t)(bm + mf * 16 + (l >> 4) * 4 + r) * 256 + w * 64 + nf * 16 + (l & 15)] =
            acc[mf][nf][r];
}

__global__ __launch_bounds__(256) void reduce_kernel(const float* __restrict__ Cp,
                                                     const float* __restrict__ bias,
                                                     float* __restrict__ out1) {
  int i = blockIdx.x * 256 + threadIdx.x;
  const size_t S = (size_t)N_GRAPHS * 256;
  float v = bias[i & 255];
#pragma unroll
  for (int s = 0; s < G2_SPLIT; s++) v += Cp[s * S + i];
  out1[i] = fmaxf(v, 0.f);
}

// ---------------------------------------------------------------- tail
__global__ __launch_bounds__(256) void tail_kernel(const float* __restrict__ out1,
                                                   const float* __restrict__ Wd2,
                                                   const float* __restrict__ bd2,
                                                   const float* __restrict__ Wd3,
                                                   const float* __restrict__ bd3,
                                                   float* __restrict__ out) {
  int lane = threadIdx.x & 63;
  int wave = threadIdx.x >> 6;
  int row = blockIdx.x * 4 + wave;

  const float* in = out1 + (size_t)row * 256;
  float i0 = in[lane];
  float i1 = in[64 + lane];
  float i2 = in[128 + lane];
  float i3 = in[192 + lane];

  float a0 = bd2[lane];
  float a1 = bd2[64 + lane];
#pragma unroll
  for (int i = 0; i < 64; i++) {
    float v0 = __shfl(i0, i);
    a0 = fmaf(v0, Wd2[(i)*128 + lane], a0);
    a1 = fmaf(v0, Wd2[(i)*128 + 64 + lane], a1);
    float v1 = __shfl(i1, i);
    a0 = fmaf(v1, Wd2[(64 + i) * 128 + lane], a0);
    a1 = fmaf(v1, Wd2[(64 + i) * 128 + 64 + lane], a1);
    float v2 = __shfl(i2, i);
    a0 = fmaf(v2, Wd2[(128 + i) * 128 + lane], a0);
    a1 = fmaf(v2, Wd2[(128 + i) * 128 + 64 + lane], a1);
    float v3 = __shfl(i3, i);
    a0 = fmaf(v3, Wd2[(192 + i) * 128 + lane], a0);
    a1 = fmaf(v3, Wd2[(192 + i) * 128 + 64 + lane], a1);
  }
  a0 = fmaxf(a0, 0.f);
  a1 = fmaxf(a1, 0.f);
  float p = a0 * Wd3[lane] + a1 * Wd3[64 + lane];
#pragma unroll
  for (int m = 32; m >= 1; m >>= 1) p += __shfl_xor(p, m);
  if (lane == 0) out[row] = 1.f / (1.f + expf(-(p + bd3[0])));
}

// ---------------------------------------------------------------- launcher
extern "C" void kernel_launch(void* const* d_in, const int* in_sizes, int n_in,
                              void* d_out, int out_size, void* d_ws, size_t ws_size,
                              hipStream_t stream) {
  const float* x        = (const float*)d_in[0];
  const int*   senders  = (const int*)d_in[1];
  const int*   receivers= (const int*)d_in[2];
  const float* W1       = (const float*)d_in[3];
  const float* b1       = (const float*)d_in[4];
  const float* gamma    = (const float*)d_in[5];
  const float* beta     = (const float*)d_in[6];
  const float* bn_mean  = (const float*)d_in[7];
  const float* bn_var   = (const float*)d_in[8];
  const float* W_d1     = (const float*)d_in[9];
  const float* b_d1     = (const float*)d_in[10];
  const float* W_d2     = (const float*)d_in[11];
  const float* b_d2     = (const float*)d_in[12];
  const float* W_d3     = (const float*)d_in[13];
  const float* b_d3     = (const float*)d_in[14];
  float* out = (float*)d_out;

  // workspace layout
  char* ws = (char*)d_ws;
  unsigned short* h_hi = (unsigned short*)ws; ws += (size_t)N_NODES * 64 * 2;  // 52.43 MB
  unsigned short* h_lo = (unsigned short*)ws; ws += (size_t)N_NODES * 64 * 2;  // 52.43 MB
  char* regB = ws;                       ws += (size_t)NPWG * NB1 * 4;         // 2.10 MB
  unsigned* wg_hist = (unsigned*)regB;
  unsigned* noff    = (unsigned*)regB;   // NB1*401*4 = 1.64 MB (after partition1)
  unsigned* gtotal  = (unsigned*)ws;     ws += NB1 * 4;
  unsigned* gbase   = (unsigned*)ws;     ws += NB1 * 4;
  unsigned short* Bt_hi = (unsigned short*)ws; ws += (size_t)256 * 6400 * 2;   // 3.28 MB
  unsigned short* Bt_lo = (unsigned short*)ws; ws += (size_t)256 * 6400 * 2;   // 3.28 MB
  char* regDE = ws;   // midrec(13.1MB)+sorted(16.8MB) -> later Cp(33.6)+out1(4.2)
  unsigned short* midrec = (unsigned short*)regDE;
  unsigned short* sorted = (unsigned short*)(regDE + (size_t)N_EDGES * 2);
  float* Cp   = (float*)regDE;
  float* out1 = (float*)(regDE + (size_t)G2_SPLIT * N_GRAPHS * 256 * 4);

  count1_kernel<<<NPWG, 256, 0, stream>>>(receivers, wg_hist);
  scan_wg_kernel<<<NB1 / 256, 256, 0, stream>>>(wg_hist, gtotal);
  scan_bucket_kernel<<<1, 256, 0, stream>>>(gtotal, gbase);
  partition1_kernel<<<NPWG, 256, 0, stream>>>(receivers, senders, wg_hist, gbase, midrec);
  sort2_kernel<<<NB1, 256, 0, stream>>>(midrec, gtotal, gbase, sorted, noff);
  wcvt_kernel<<<dim3(100, 4), 256, 0, stream>>>(W_d1, Bt_hi, Bt_lo);
  aggconv_kernel<<<N_GRAPHS, 256, 0, stream>>>(x, noff, sorted, W1, b1,
                                               gamma, beta, bn_mean, bn_var, h_hi, h_lo);
  gemm2_kernel<<<dim3(N_GRAPHS / 64, G2_SPLIT), 256, 0, stream>>>(h_hi, h_lo, Bt_hi, Bt_lo, Cp);
  reduce_kernel<<<(N_GRAPHS * 256) / 256, 256, 0, stream>>>(Cp, b_d1, out1);
  tail_kernel<<<N_GRAPHS / 4, 256, 0, stream>>>(out1, W_d2, b_d2, W_d3, b_d3, out);
}

// Round 12
// 511.499 us; speedup vs baseline: 5.7760x; 1.0057x over previous
//
#include <hip/hip_runtime.h>
#include <cstdint>
#include <cstddef>

#define GRAPH_SIZE 100
#define N_GRAPHS 4096
#define N_NODES (N_GRAPHS * GRAPH_SIZE)   // 409600
#define DEG 16
#define N_EDGES (N_NODES * DEG)           // 6553600
#define BN_EPS 1e-3f

#define NB 4096                   // one bucket per graph
#define PCHUNK 12800              // edges per partition WG
#define NPWG (N_EDGES / PCHUNK)   // 512
#define ESTRIDE 2048              // fixed per-graph edge slot capacity

typedef __attribute__((ext_vector_type(8))) unsigned short ushort8;
typedef __attribute__((ext_vector_type(8))) short short8;
typedef __attribute__((ext_vector_type(4))) float f32x4;

__device__ __forceinline__ unsigned f2bf(float f) {   // RNE float->bf16 bits
  unsigned u = __float_as_uint(f);
  return (u + 0x7FFFu + ((u >> 16) & 1u)) >> 16;
}
__device__ __forceinline__ float bf2f(unsigned h) {
  return __uint_as_float(h << 16);
}
__device__ __forceinline__ short8 cvt8(float4 a, float4 b) {
  short8 r;
  r[0] = (short)f2bf(a.x); r[1] = (short)f2bf(a.y);
  r[2] = (short)f2bf(a.z); r[3] = (short)f2bf(a.w);
  r[4] = (short)f2bf(b.x); r[5] = (short)f2bf(b.y);
  r[6] = (short)f2bf(b.z); r[7] = (short)f2bf(b.w);
  return r;
}

// ---------------------------------------------------------------- count1
__global__ __launch_bounds__(256) void count1_kernel(const int* __restrict__ recv,
                                                     unsigned* __restrict__ wg_hist) {
  __shared__ unsigned lh[NB];
  int tid = threadIdx.x, w = blockIdx.x;
  for (int i = tid; i < NB; i += 256) lh[i] = 0;
  __syncthreads();
  size_t base = (size_t)w * PCHUNK;
  for (int i = tid; i < PCHUNK; i += 256)
    atomicAdd(&lh[(unsigned)recv[base + i] / GRAPH_SIZE], 1u);
  __syncthreads();
  for (int i = tid; i < NB; i += 256) wg_hist[(size_t)w * NB + i] = lh[i];
}

// wg_hist[w][g] -> exclusive prefix over w (per graph); per-graph totals out.
__global__ __launch_bounds__(256) void scan_wg_kernel(unsigned* __restrict__ wg_hist,
                                                      unsigned* __restrict__ gtotal) {
  int b = blockIdx.x * 256 + threadIdx.x;   // grid = NB/256 = 16
  unsigned run = 0;
  for (int w = 0; w < NPWG; w++) {
    size_t idx = (size_t)w * NB + b;
    unsigned c = wg_hist[idx];
    wg_hist[idx] = run;
    run += c;
  }
  gtotal[b] = run;
}

// ---------------------------------------------------------------- partition1
// LDS counting-sort of each 12800-edge chunk into 4096 graph buckets.
// u16 record = sl(7b)<<7 | rl(7b). Fixed per-graph stride ESTRIDE.
// blockIdx XCD-swizzled so adjacent-offset writers share an XCD L2.
__global__ __launch_bounds__(256) void partition1_kernel(const int* __restrict__ recv,
                                                         const int* __restrict__ send,
                                                         const unsigned* __restrict__ wg_hist,
                                                         unsigned short* __restrict__ edges) {
  __shared__ unsigned cur[NB];          // 16 KB
  __shared__ unsigned tmp[256];
  __shared__ unsigned stage[PCHUNK];    // 51.2 KB
  int tid = threadIdx.x;
  int w = (blockIdx.x & 7) * (NPWG / 8) + (blockIdx.x >> 3);   // bijective: 512 = 8*64
  size_t base = (size_t)w * PCHUNK;

  for (int i = tid; i < NB; i += 256) cur[i] = 0;
  __syncthreads();
  for (int i = tid; i < PCHUNK; i += 256)
    atomicAdd(&cur[(unsigned)recv[base + i] / GRAPH_SIZE], 1u);
  __syncthreads();

  // exclusive scan of cur[4096]
  unsigned my[16], s16 = 0;
#pragma unroll
  for (int j = 0; j < 16; j++) { my[j] = cur[tid * 16 + j]; s16 += my[j]; }
  tmp[tid] = s16;
  __syncthreads();
  unsigned acc = s16;
  for (int d = 1; d < 256; d <<= 1) {
    unsigned t = (tid >= d) ? tmp[tid - d] : 0;
    __syncthreads();
    acc += t;
    tmp[tid] = acc;
    __syncthreads();
  }
  unsigned run = acc - s16;
#pragma unroll
  for (int j = 0; j < 16; j++) { cur[tid * 16 + j] = run; run += my[j]; }
  __syncthreads();

  for (int i = tid; i < PCHUNK; i += 256) {
    unsigned r = (unsigned)recv[base + i];
    unsigned s = (unsigned)send[base + i];
    unsigned g = r / GRAPH_SIZE;
    unsigned rl = r - g * GRAPH_SIZE;
    unsigned sl = s - (s / GRAPH_SIZE) * GRAPH_SIZE;
    unsigned pos = atomicAdd(&cur[g], 1u);
    stage[pos] = (g << 16) | (sl << 7) | rl;
  }
  __syncthreads();
  // cur[g] == exclusive end of bucket g within this chunk

  const unsigned* wrow = wg_hist + (size_t)w * NB;
  for (int p = tid; p < PCHUNK; p += 256) {
    unsigned rec = stage[p];
    unsigned g = rec >> 16;
    unsigned start = (g > 0) ? cur[g - 1] : 0;
    unsigned local = wrow[g] + ((unsigned)p - start);
    if (local < ESTRIDE)
      edges[(size_t)g * ESTRIDE + local] = (unsigned short)(rec & 0x3FFFu);
  }
}

// ---------------------------------------------------------------- W1 cvt
// W1[in][out] f32 -> W1t_hi/lo[out][in] bf16 planes (16 KB total, L2-hot)
__global__ __launch_bounds__(256) void w1cvt_kernel(const float* __restrict__ W1,
                                                    unsigned short* __restrict__ Whi,
                                                    unsigned short* __restrict__ Wlo) {
  int tid = threadIdx.x;
  for (int idx = tid; idx < 4096; idx += 256) {
    int o = idx >> 6, i = idx & 63;
    float f = W1[i * 64 + o];
    unsigned hb = f2bf(f);
    Whi[o * 64 + i] = (unsigned short)hb;
    Wlo[o * 64 + i] = (unsigned short)f2bf(f - bf2f(hb));
  }
}

// --------------------------------------------- aggconv via MFMA
// One WG (256 thr) per graph, 2 WG/CU.
//   S[100][104] f32 count matrix via LDS atomics (exact ints -> exact bf16)
//   MFMA1: agg = S @ (Xhi + Xlo)   [m=node 112pad][k=node 128pad][n=ch 64]
//   MFMA2: h = (Ahi+Alo) @ (Whi+Wlo) 3-product, BN folded, ELU, split write
__global__ __launch_bounds__(256) void aggconv_kernel(
    const float* __restrict__ x, const unsigned* __restrict__ gtotal,
    const unsigned short* __restrict__ edges,
    const unsigned short* __restrict__ W1t_hi, const unsigned short* __restrict__ W1t_lo,
    const float* __restrict__ b1, const float* __restrict__ gamma,
    const float* __restrict__ beta, const float* __restrict__ bn_mean,
    const float* __restrict__ bn_var,
    unsigned short* __restrict__ h_hi, unsigned short* __restrict__ h_lo) {
  __shared__ __align__(16) float S[100 * 104];             // 41.6 KB
  __shared__ __align__(16) unsigned short Xhi[64 * 104];   // 13.3 KB  [ch][k=node]
  __shared__ __align__(16) unsigned short Xlo[64 * 104];   // 13.3 KB
  __shared__ __align__(16) unsigned short es_s[ESTRIDE];   // 4 KB
  __shared__ float prm[128];                               // sc[64], sh[64]
  __shared__ __align__(16) unsigned short zslot[16];       // 32 B zeros

  int tid = threadIdx.x, lane = tid & 63, wv = tid >> 6;
  int l15 = lane & 15, hg = lane >> 4;
  int g = blockIdx.x;
  size_t gb64 = (size_t)g * 6400;

  // prefetch W1 fragments (consumed in MFMA2; hides full pipeline latency)
  short8 wfh[4][2], wfl[4][2];
#pragma unroll
  for (int nf = 0; nf < 4; nf++)
#pragma unroll
    for (int ks = 0; ks < 2; ks++) {
      int o = nf * 16 + l15, k = ks * 32 + hg * 8;
      wfh[nf][ks] = *(const short8*)&W1t_hi[o * 64 + k];
      wfl[nf][ks] = *(const short8*)&W1t_lo[o * 64 + k];
    }

  // ---- P1: zero S, stage Xt planes, edges, params
  {
    float4 z4 = {0.f, 0.f, 0.f, 0.f};
    float4* S4 = (float4*)S;
    for (int i = tid; i < 2600; i += 256) S4[i] = z4;
  }
#pragma unroll
  for (int j = 0; j < 25; j++) {
    int i = tid + 256 * j;
    float v = x[gb64 + i];
    int node = i >> 6, ch = i & 63;
    unsigned hb = f2bf(v);
    Xhi[ch * 104 + node] = (unsigned short)hb;
    Xlo[ch * 104 + node] = (unsigned short)f2bf(v - bf2f(hb));
  }
  if (tid < 64) {
#pragma unroll
    for (int c = 100; c < 104; c++) { Xhi[tid * 104 + c] = 0; Xlo[tid * 104 + c] = 0; }
    float sc = gamma[tid] * rsqrtf(bn_var[tid] + BN_EPS);
    prm[tid] = sc;
    prm[64 + tid] = (b1[tid] - bn_mean[tid]) * sc + beta[tid];
  }
  if (tid < 16) zslot[tid] = 0;
  unsigned cnt = gtotal[g];
  if (cnt > ESTRIDE) cnt = ESTRIDE;
  {
    const unsigned* e32 = (const unsigned*)(edges + (size_t)g * ESTRIDE);
    unsigned* d32 = (unsigned*)es_s;
    unsigned n32 = (cnt + 1) >> 1;
    for (unsigned i = tid; i < n32; i += 256) d32[i] = e32[i];
  }
  __syncthreads();

  // ---- P2: build S (integer counts, order-independent in fp32)
  for (unsigned e = tid; e < cnt; e += 256) {
    unsigned rec = es_s[e];
    atomicAdd(&S[(rec & 127u) * 104 + (rec >> 7)], 1.0f);
  }
  __syncthreads();

  // ---- P3: MFMA1  agg = S @ X (X split hi/lo; S exact)
  int mts[2];
  mts[0] = wv;
  mts[1] = (wv < 3) ? 4 + wv : 6;   // tiles 0..6; tile 6 duplicated (benign)
  f32x4 acc1[2][4];
#pragma unroll
  for (int mi = 0; mi < 2; mi++)
#pragma unroll
    for (int nf = 0; nf < 4; nf++) acc1[mi][nf] = (f32x4){0.f, 0.f, 0.f, 0.f};

#pragma unroll
  for (int ks = 0; ks < 4; ks++) {
    int k0 = ks * 32 + hg * 8;
    bool kv = (k0 <= 96);            // k0>96 lane-groups read zeros
    short8 bh[4], bl[4];
#pragma unroll
    for (int nf = 0; nf < 4; nf++) {
      int col = nf * 16 + l15;
      const unsigned short* ph = kv ? &Xhi[col * 104 + k0] : zslot;
      const unsigned short* pl = kv ? &Xlo[col * 104 + k0] : zslot;
      bh[nf] = *(const short8*)ph;
      bl[nf] = *(const short8*)pl;
    }
#pragma unroll
    for (int mi = 0; mi < 2; mi++) {
      int row = mts[mi] * 16 + l15;
      const float* ap = kv ? &S[row * 104 + k0] : (const float*)zslot;
      float4 a0 = *(const float4*)ap;
      float4 a1 = *(const float4*)(ap + 4);
      short8 af = cvt8(a0, a1);
#pragma unroll
      for (int nf = 0; nf < 4; nf++) {
        acc1[mi][nf] = __builtin_amdgcn_mfma_f32_16x16x32_bf16(af, bh[nf], acc1[mi][nf], 0, 0, 0);
        acc1[mi][nf] = __builtin_amdgcn_mfma_f32_16x16x32_bf16(af, bl[nf], acc1[mi][nf], 0, 0, 0);
      }
    }
  }
  __syncthreads();   // S/Xt reads done -> safe to overwrite S with agg planes

  // ---- P4: write agg as bf16 hi/lo planes over dead S region
  unsigned short* Ahi = (unsigned short*)S;            // [112][72]
  unsigned short* Alo = Ahi + 112 * 72;                // 32.3 KB total <= 41.6
#pragma unroll
  for (int mi = 0; mi < 2; mi++)
#pragma unroll
    for (int nf = 0; nf < 4; nf++)
#pragma unroll
      for (int r = 0; r < 4; r++) {
        float v = acc1[mi][nf][r];
        int m = mts[mi] * 16 + hg * 4 + r;
        int kc = nf * 16 + l15;
        unsigned hb = f2bf(v);
        Ahi[m * 72 + kc] = (unsigned short)hb;
        Alo[m * 72 + kc] = (unsigned short)f2bf(v - bf2f(hb));
      }
  __syncthreads();

  // ---- P5: MFMA2  h = agg @ W1 (3-product split)
  f32x4 acc2[2][4];
#pragma unroll
  for (int mi = 0; mi < 2; mi++)
#pragma unroll
    for (int nf = 0; nf < 4; nf++) acc2[mi][nf] = (f32x4){0.f, 0.f, 0.f, 0.f};
#pragma unroll
  for (int ks = 0; ks < 2; ks++) {
    int k0 = ks * 32 + hg * 8;
#pragma unroll
    for (int mi = 0; mi < 2; mi++) {
      int row = mts[mi] * 16 + l15;
      short8 ah = *(const short8*)&Ahi[row * 72 + k0];
      short8 al = *(const short8*)&Alo[row * 72 + k0];
#pragma unroll
      for (int nf = 0; nf < 4; nf++) {
        acc2[mi][nf] = __builtin_amdgcn_mfma_f32_16x16x32_bf16(ah, wfh[nf][ks], acc2[mi][nf], 0, 0, 0);
        acc2[mi][nf] = __builtin_amdgcn_mfma_f32_16x16x32_bf16(ah, wfl[nf][ks], acc2[mi][nf], 0, 0, 0);
        acc2[mi][nf] = __builtin_amdgcn_mfma_f32_16x16x32_bf16(al, wfh[nf][ks], acc2[mi][nf], 0, 0, 0);
      }
    }
  }

  // ---- P6: epilogue BN(folded)+ELU+split-bf16 store
  float scv[4], shv[4];
#pragma unroll
  for (int nf = 0; nf < 4; nf++) {
    scv[nf] = prm[nf * 16 + l15];
    shv[nf] = prm[64 + nf * 16 + l15];
  }
#pragma unroll
  for (int mi = 0; mi < 2; mi++)
#pragma unroll
    for (int nf = 0; nf < 4; nf++)
#pragma unroll
      for (int r = 0; r < 4; r++) {
        int node = mts[mi] * 16 + hg * 4 + r;
        if (node < 100) {
          float v = fmaf(acc2[mi][nf][r], scv[nf], shv[nf]);
          v = (v > 0.f) ? v : (__expf(v) - 1.f);
          unsigned hb = f2bf(v);
          size_t idx = gb64 + (size_t)node * 64 + nf * 16 + l15;
          h_hi[idx] = (unsigned short)hb;
          h_lo[idx] = (unsigned short)f2bf(v - bf2f(hb));
        }
      }
}

// ---------------------------------------------------------------- W_d1 cvt
__global__ __launch_bounds__(256) void wcvt_kernel(const float* __restrict__ W,
                                                   unsigned short* __restrict__ Bhi,
                                                   unsigned short* __restrict__ Blo) {
  __shared__ float sm[64][65];
  int tid = threadIdx.x;
  int k0 = blockIdx.x * 64;    // 100
  int n0 = blockIdx.y * 64;    // 4
  for (int i = tid; i < 1024; i += 256) {
    int r = i >> 4, c4 = i & 15;
    float4 v = *(const float4*)&W[(size_t)(k0 + r) * 256 + n0 + c4 * 4];
    sm[r][c4 * 4 + 0] = v.x; sm[r][c4 * 4 + 1] = v.y;
    sm[r][c4 * 4 + 2] = v.z; sm[r][c4 * 4 + 3] = v.w;
  }
  __syncthreads();
  for (int i = tid; i < 512; i += 256) {
    int nn = i >> 3, kk = i & 7;
    ushort8 hi, lo;
#pragma unroll
    for (int j = 0; j < 8; j++) {
      float f = sm[kk * 8 + j][nn];
      unsigned hb = f2bf(f);
      hi[j] = (unsigned short)hb;
      lo[j] = (unsigned short)f2bf(f - bf2f(hb));
    }
    size_t o = (size_t)(n0 + nn) * 6400 + k0 + kk * 8;
    *(ushort8*)&Bhi[o] = hi;
    *(ushort8*)&Blo[o] = lo;
  }
}

// ---------------------------------------------------------------- GEMM2 (MFMA)
#define G2_SPLIT 8
#define G2_KSLICE 800
#define G2_STEPS (G2_KSLICE / 32)   // 25
__global__ __launch_bounds__(256) void gemm2_kernel(const unsigned short* __restrict__ Ahi,
                                                    const unsigned short* __restrict__ Alo,
                                                    const unsigned short* __restrict__ Bhi,
                                                    const unsigned short* __restrict__ Blo,
                                                    float* __restrict__ Cp) {
  __shared__ __align__(16) unsigned short As[2][64 * 40];
  __shared__ __align__(16) unsigned short Bs[2][256 * 40];
  int tid = threadIdx.x;
  int w = tid >> 6, l = tid & 63;
  int bm = blockIdx.x * 64;
  int kslice = blockIdx.y * G2_KSLICE;

  f32x4 acc[4][4];
#pragma unroll
  for (int i = 0; i < 4; i++)
#pragma unroll
    for (int j = 0; j < 4; j++) acc[i][j] = (f32x4){0.f, 0.f, 0.f, 0.f};

  int arow = tid >> 2, akg = tid & 3;
  const size_t abase = (size_t)(bm + arow) * 6400 + kslice + akg * 8;

  ushort8 pa_hi, pa_lo, pb_hi[4], pb_lo[4];
  pa_hi = *(const ushort8*)&Ahi[abase];
  pa_lo = *(const ushort8*)&Alo[abase];
#pragma unroll
  for (int i = 0; i < 4; i++) {
    int u = tid + 256 * i;
    size_t bb = (size_t)(u >> 2) * 6400 + kslice + (u & 3) * 8;
    pb_hi[i] = *(const ushort8*)&Bhi[bb];
    pb_lo[i] = *(const ushort8*)&Blo[bb];
  }

  for (int step = 0; step < G2_STEPS; step++) {
    __syncthreads();
    *(ushort8*)&As[0][arow * 40 + akg * 8] = pa_hi;
    *(ushort8*)&As[1][arow * 40 + akg * 8] = pa_lo;
#pragma unroll
    for (int i = 0; i < 4; i++) {
      int u = tid + 256 * i;
      *(ushort8*)&Bs[0][(u >> 2) * 40 + (u & 3) * 8] = pb_hi[i];
      *(ushort8*)&Bs[1][(u >> 2) * 40 + (u & 3) * 8] = pb_lo[i];
    }
    __syncthreads();

    if (step + 1 < G2_STEPS) {
      size_t koff = (size_t)(step + 1) * 32;
      pa_hi = *(const ushort8*)&Ahi[abase + koff];
      pa_lo = *(const ushort8*)&Alo[abase + koff];
#pragma unroll
      for (int i = 0; i < 4; i++) {
        int u = tid + 256 * i;
        size_t bb = (size_t)(u >> 2) * 6400 + kslice + (u & 3) * 8 + koff;
        pb_hi[i] = *(const ushort8*)&Bhi[bb];
        pb_lo[i] = *(const ushort8*)&Blo[bb];
      }
    }

    int kg8 = (l >> 4) * 8;
    short8 a_hi[4], a_lo[4];
#pragma unroll
    for (int mf = 0; mf < 4; mf++) {
      int r = mf * 16 + (l & 15);
      a_hi[mf] = *(const short8*)&As[0][r * 40 + kg8];
      a_lo[mf] = *(const short8*)&As[1][r * 40 + kg8];
    }
#pragma unroll
    for (int nf = 0; nf < 4; nf++) {
      int c = w * 64 + nf * 16 + (l & 15);
      short8 b_hi = *(const short8*)&Bs[0][c * 40 + kg8];
      short8 b_lo = *(const short8*)&Bs[1][c * 40 + kg8];
#pragma unroll
      for (int mf = 0; mf < 4; mf++) {
        acc[mf][nf] = __builtin_amdgcn_mfma_f32_16x16x32_bf16(a_hi[mf], b_hi, acc[mf][nf], 0, 0, 0);
        acc[mf][nf] = __builtin_amdgcn_mfma_f32_16x16x32_bf16(a_hi[mf], b_lo, acc[mf][nf], 0, 0, 0);
        acc[mf][nf] = __builtin_amdgcn_mfma_f32_16x16x32_bf16(a_lo[mf], b_hi, acc[mf][nf], 0, 0, 0);
      }
    }
  }

  float* outp = Cp + (size_t)blockIdx.y * N_GRAPHS * 256;
#pragma unroll
  for (int mf = 0; mf < 4; mf++)
#pragma unroll
    for (int nf = 0; nf < 4; nf++)
#pragma unroll
      for (int r = 0; r < 4; r++)
        outp[(size_t)(bm + mf * 16 + (l >> 4) * 4 + r) * 256 + w * 64 + nf * 16 + (l & 15)] =
            acc[mf][nf][r];
}

__global__ __launch_bounds__(256) void reduce_kernel(const float* __restrict__ Cp,
                                                     const float* __restrict__ bias,
                                                     float* __restrict__ out1) {
  int i = blockIdx.x * 256 + threadIdx.x;
  const size_t S = (size_t)N_GRAPHS * 256;
  float v = bias[i & 255];
#pragma unroll
  for (int s = 0; s < G2_SPLIT; s++) v += Cp[s * S + i];
  out1[i] = fmaxf(v, 0.f);
}

// ---------------------------------------------------------------- tail
__global__ __launch_bounds__(256) void tail_kernel(const float* __restrict__ out1,
                                                   const float* __restrict__ Wd2,
                                                   const float* __restrict__ bd2,
                                                   const float* __restrict__ Wd3,
                                                   const float* __restrict__ bd3,
                                                   float* __restrict__ out) {
  int lane = threadIdx.x & 63;
  int wave = threadIdx.x >> 6;
  int row = blockIdx.x * 4 + wave;

  const float* in = out1 + (size_t)row * 256;
  float i0 = in[lane];
  float i1 = in[64 + lane];
  float i2 = in[128 + lane];
  float i3 = in[192 + lane];

  float a0 = bd2[lane];
  float a1 = bd2[64 + lane];
#pragma unroll
  for (int i = 0; i < 64; i++) {
    float v0 = __shfl(i0, i);
    a0 = fmaf(v0, Wd2[(i)*128 + lane], a0);
    a1 = fmaf(v0, Wd2[(i)*128 + 64 + lane], a1);
    float v1 = __shfl(i1, i);
    a0 = fmaf(v1, Wd2[(64 + i) * 128 + lane], a0);
    a1 = fmaf(v1, Wd2[(64 + i) * 128 + 64 + lane], a1);
    float v2 = __shfl(i2, i);
    a0 = fmaf(v2, Wd2[(128 + i) * 128 + lane], a0);
    a1 = fmaf(v2, Wd2[(128 + i) * 128 + 64 + lane], a1);
    float v3 = __shfl(i3, i);
    a0 = fmaf(v3, Wd2[(192 + i) * 128 + lane], a0);
    a1 = fmaf(v3, Wd2[(192 + i) * 128 + 64 + lane], a1);
  }
  a0 = fmaxf(a0, 0.f);
  a1 = fmaxf(a1, 0.f);
  float p = a0 * Wd3[lane] + a1 * Wd3[64 + lane];
#pragma unroll
  for (int m = 32; m >= 1; m >>= 1) p += __shfl_xor(p, m);
  if (lane == 0) out[row] = 1.f / (1.f + expf(-(p + bd3[0])));
}

// ---------------------------------------------------------------- launcher
extern "C" void kernel_launch(void* const* d_in, const int* in_sizes, int n_in,
                              void* d_out, int out_size, void* d_ws, size_t ws_size,
                              hipStream_t stream) {
  const float* x        = (const float*)d_in[0];
  const int*   senders  = (const int*)d_in[1];
  const int*   receivers= (const int*)d_in[2];
  const float* W1       = (const float*)d_in[3];
  const float* b1       = (const float*)d_in[4];
  const float* gamma    = (const float*)d_in[5];
  const float* beta     = (const float*)d_in[6];
  const float* bn_mean  = (const float*)d_in[7];
  const float* bn_var   = (const float*)d_in[8];
  const float* W_d1     = (const float*)d_in[9];
  const float* b_d1     = (const float*)d_in[10];
  const float* W_d2     = (const float*)d_in[11];
  const float* b_d2     = (const float*)d_in[12];
  const float* W_d3     = (const float*)d_in[13];
  const float* b_d3     = (const float*)d_in[14];
  float* out = (float*)d_out;

  // workspace layout
  char* ws = (char*)d_ws;
  unsigned short* h_hi = (unsigned short*)ws; ws += (size_t)N_NODES * 64 * 2;  // 52.43 MB
  unsigned short* h_lo = (unsigned short*)ws; ws += (size_t)N_NODES * 64 * 2;  // 52.43 MB
  unsigned* gtotal = (unsigned*)ws;           ws += NB * 4;                    // 16 KB
  unsigned short* Bt_hi = (unsigned short*)ws; ws += (size_t)256 * 6400 * 2;   // 3.28 MB
  unsigned short* Bt_lo = (unsigned short*)ws; ws += (size_t)256 * 6400 * 2;   // 3.28 MB
  unsigned short* W1t_hi = (unsigned short*)ws; ws += 4096 * 2;
  unsigned short* W1t_lo = (unsigned short*)ws; ws += 4096 * 2;
  // region: [wg_hist 8.39MB | edges 16.78MB]  aliased later by [Cp 33.55MB | out1 4.19MB]
  char* region = ws;
  unsigned* wg_hist = (unsigned*)region;                                    // 512*4096*4
  unsigned short* edges = (unsigned short*)(region + (size_t)NPWG * NB * 4);
  float* Cp   = (float*)region;
  float* out1 = (float*)(region + (size_t)G2_SPLIT * N_GRAPHS * 256 * 4);

  count1_kernel<<<NPWG, 256, 0, stream>>>(receivers, wg_hist);
  scan_wg_kernel<<<NB / 256, 256, 0, stream>>>(wg_hist, gtotal);
  partition1_kernel<<<NPWG, 256, 0, stream>>>(receivers, senders, wg_hist, edges);
  w1cvt_kernel<<<1, 256, 0, stream>>>(W1, W1t_hi, W1t_lo);
  wcvt_kernel<<<dim3(100, 4), 256, 0, stream>>>(W_d1, Bt_hi, Bt_lo);
  aggconv_kernel<<<N_GRAPHS, 256, 0, stream>>>(x, gtotal, edges, W1t_hi, W1t_lo,
                                               b1, gamma, beta, bn_mean, bn_var, h_hi, h_lo);
  gemm2_kernel<<<dim3(N_GRAPHS / 64, G2_SPLIT), 256, 0, stream>>>(h_hi, h_lo, Bt_hi, Bt_lo, Cp);
  reduce_kernel<<<(N_GRAPHS * 256) / 256, 256, 0, stream>>>(Cp, b_d1, out1);
  tail_kernel<<<N_GRAPHS / 4, 256, 0, stream>>>(out1, W_d2, b_d2, W_d3, b_d3, out);
}